// Round 6
// baseline (272.158 us; speedup 1.0000x reference)
//
#include <hip/hip_runtime.h>

// ---------------------------------------------------------------------------
// K1: conv1 (11x11, 50->40) + maxpool2 + relu, 4 blocks per sample.
// (unchanged from round 4)
// ---------------------------------------------------------------------------
__global__ __launch_bounds__(128) void conv1_kernel(
    const float* __restrict__ x_img, const float* __restrict__ cw1,
    const float* __restrict__ cb1, float* __restrict__ h1)
{
    const int blk = blockIdx.x;
    const int b = blk >> 2;
    const int c = blk & 3;
    const int tid = threadIdx.x;

    __shared__ __align__(16) float s_img[1000];

    const float* img = x_img + (size_t)b * 2500 + (size_t)(10 * c) * 50;
    for (int i = tid; i < 1000; i += 128) s_img[i] = img[i];
    __syncthreads();

    if (tid < 100) {
        const int ly = tid / 20, px = tid % 20;
        const int py = 5 * c + ly;
        const int C = 2 * px;
        float acc0[10], acc1[10], acc2[10], acc3[10];
        #pragma unroll
        for (int oc = 0; oc < 10; ++oc) { acc0[oc] = 0.f; acc1[oc] = 0.f; acc2[oc] = 0.f; acc3[oc] = 0.f; }
        for (int r = 0; r < 12; ++r) {
            float v[12];
            #pragma unroll
            for (int j = 0; j < 6; ++j) {
                float2 t = *(const float2*)&s_img[(2 * ly + r) * 50 + C + 2 * j];
                v[2 * j] = t.x; v[2 * j + 1] = t.y;
            }
            if (r < 11) {
                #pragma unroll
                for (int oc = 0; oc < 10; ++oc) {
                    #pragma unroll
                    for (int kx = 0; kx < 11; ++kx) {
                        float w0 = cw1[oc * 121 + r * 11 + kx];
                        acc0[oc] = fmaf(v[kx], w0, acc0[oc]);
                        acc1[oc] = fmaf(v[kx + 1], w0, acc1[oc]);
                    }
                }
            }
            if (r >= 1) {
                #pragma unroll
                for (int oc = 0; oc < 10; ++oc) {
                    #pragma unroll
                    for (int kx = 0; kx < 11; ++kx) {
                        float w1 = cw1[oc * 121 + (r - 1) * 11 + kx];
                        acc2[oc] = fmaf(v[kx], w1, acc2[oc]);
                        acc3[oc] = fmaf(v[kx + 1], w1, acc3[oc]);
                    }
                }
            }
        }
        float* hb = h1 + (size_t)b * 4000 + py * 20 + px;
        #pragma unroll
        for (int oc = 0; oc < 10; ++oc) {
            float m = fmaxf(fmaxf(acc0[oc], acc1[oc]), fmaxf(acc2[oc], acc3[oc]));
            hb[oc * 400] = fmaxf(m + cb1[oc], 0.f);
        }
    }
}

// ---------------------------------------------------------------------------
// LP structure tables (verified rounds 3-5).
// ---------------------------------------------------------------------------
__device__ const signed char AZ_IDX[32][8] = {
    {4,5,6,7,8,9,0,0},{10,11,0,0,0,0,0,0},{4,5,6,7,8,9,10,11},
    {0,12,14,0,0,0,0,0},{2,12,14,0,0,0,0,0},{12,14,0,0,0,0,0,0},
    {1,13,15,0,0,0,0,0},{3,13,15,0,0,0,0,0},{13,15,0,0,0,0,0,0},
    {16,18,4,0,0,0,0,0},{16,18,6,0,0,0,0,0},{17,19,5,0,0,0,0,0},
    {17,19,7,0,0,0,0,0},{20,21,8,0,0,0,0,0},{20,21,10,0,0,0,0,0},
    {22,23,9,0,0,0,0,0},{22,23,11,0,0,0,0,0},
    {0},{0},{0},{0},{0},{0},{0},{0},{0},{0},{0},{0},{0},{0},{0}
};
__device__ const signed char AZ_SEL[32][8] = {
    {1,1,1,1,1,1,0,0},{1,1,0,0,0,0,0,0},{3,4,5,6,7,8,9,10},
    {1,11,13,0,0,0,0,0},{1,12,14,0,0,0,0,0},{1,1,0,0,0,0,0,0},
    {1,13,15,0,0,0,0,0},{1,14,16,0,0,0,0,0},{1,1,0,0,0,0,0,0},
    {17,19,2,0,0,0,0,0},{18,20,2,0,0,0,0,0},{19,21,2,0,0,0,0,0},
    {20,22,2,0,0,0,0,0},{23,25,2,0,0,0,0,0},{24,26,2,0,0,0,0,0},
    {27,29,2,0,0,0,0,0},{28,30,2,0,0,0,0,0},
    {0},{0},{0},{0},{0},{0},{0},{0},{0},{0},{0},{0},{0},{0},{0}
};
__device__ const signed char AT_IDX[32][3] = {
    {3,0,0},{6,0,0},{4,0,0},{7,0,0},
    {0,2,9},{0,2,11},{0,2,10},{0,2,12},{0,2,13},{0,2,15},{1,2,14},{1,2,16},
    {3,4,5},{6,7,8},{3,4,5},{6,7,8},
    {9,10,0},{11,12,0},{9,10,0},{11,12,0},
    {13,14,0},{13,14,0},{15,16,0},{15,16,0},
    {0},{0},{0},{0},{0},{0},{0},{0}
};
__device__ const signed char M_IDX[32][10] = {
    {0,12,14,0,0,0,0,0,0,0},
    {1,13,15,0,0,0,0,0,0,0},
    {2,12,14,0,0,0,0,0,0,0},
    {3,13,15,0,0,0,0,0,0,0},
    {4,5,6,7,8,9,10,11,16,18},
    {4,5,6,7,8,9,10,11,17,19},
    {4,5,6,7,8,9,10,11,16,18},
    {4,5,6,7,8,9,10,11,17,19},
    {4,5,6,7,8,9,10,11,20,21},
    {4,5,6,7,8,9,10,11,22,23},
    {4,5,6,7,8,9,10,11,20,21},
    {4,5,6,7,8,9,10,11,22,23},
    {0,2,12,14,0,0,0,0,0,0},
    {1,3,13,15,0,0,0,0,0,0},
    {0,2,12,14,0,0,0,0,0,0},
    {1,3,13,15,0,0,0,0,0,0},
    {4,6,16,18,0,0,0,0,0,0},
    {5,7,17,19,0,0,0,0,0,0},
    {4,6,16,18,0,0,0,0,0,0},
    {5,7,17,19,0,0,0,0,0,0},
    {8,10,20,21,0,0,0,0,0,0},
    {8,10,20,21,0,0,0,0,0,0},
    {9,11,22,23,0,0,0,0,0,0},
    {9,11,22,23,0,0,0,0,0,0},
    {0},{0},{0},{0},{0},{0},{0},{0}
};
__device__ const signed char M_MSK[32][10] = {
    {1,1,1,0,0,0,0,0,0,0},
    {1,1,1,0,0,0,0,0,0,0},
    {1,1,1,0,0,0,0,0,0,0},
    {1,1,1,0,0,0,0,0,0,0},
    {1,1,1,1,1,1,1,1,1,1},
    {1,1,1,1,1,1,1,1,1,1},
    {1,1,1,1,1,1,1,1,1,1},
    {1,1,1,1,1,1,1,1,1,1},
    {1,1,1,1,1,1,1,1,1,1},
    {1,1,1,1,1,1,1,1,1,1},
    {1,1,1,1,1,1,1,1,1,1},
    {1,1,1,1,1,1,1,1,1,1},
    {1,1,1,1,0,0,0,0,0,0},
    {1,1,1,1,0,0,0,0,0,0},
    {1,1,1,1,0,0,0,0,0,0},
    {1,1,1,1,0,0,0,0,0,0},
    {1,1,1,1,0,0,0,0,0,0},
    {1,1,1,1,0,0,0,0,0,0},
    {1,1,1,1,0,0,0,0,0,0},
    {1,1,1,1,0,0,0,0,0,0},
    {1,1,1,1,0,0,0,0,0,0},
    {1,1,1,1,0,0,0,0,0,0},
    {1,1,1,1,0,0,0,0,0,0},
    {1,1,1,1,0,0,0,0,0,0},
    {0},{0},{0},{0},{0},{0},{0},{0}
};

// ---------------------------------------------------------------------------
// K2: head (conv2 + dense + MLPs) FUSED with the 5 per-t LP solves.
// LP phase: threads 0..159 = 5 problems x 32 lanes, all sync intra-wave
// (DS ops are in-order per wave). LP scratch overlaid on dead s_h1.
// ---------------------------------------------------------------------------
__global__ __launch_bounds__(320) void head_lp_kernel(
    const float* __restrict__ xtraj, const float* __restrict__ x,
    const float* __restrict__ h1g,
    const float* __restrict__ cw2, const float* __restrict__ cb2,
    const float* __restrict__ w3, const float* __restrict__ b3,
    const float* __restrict__ w4, const float* __restrict__ b4,
    const float* __restrict__ pw1, const float* __restrict__ pb1,
    const float* __restrict__ pw2, const float* __restrict__ pb2,
    const float* __restrict__ pw3, const float* __restrict__ pb3,
    const float* __restrict__ vw1, const float* __restrict__ vb1,
    const float* __restrict__ vw2, const float* __restrict__ vb2,
    const float* __restrict__ vw3, const float* __restrict__ vb3,
    float* __restrict__ out)
{
    const int b = blockIdx.x;
    const int tid = threadIdx.x;

    __shared__ __align__(16) float s_h1[4000];   // conv2 input; later LP scratch
    __shared__ __align__(16) float s_w2[5000];
    __shared__ __align__(16) float s_h2[320];
    __shared__ float s_hc[145];
    __shared__ float s_t1[152];
    __shared__ float s_m1[256];
    __shared__ float s_m2[256];

    // LP scratch overlay on s_h1 (dead after conv2 phase):
    //   [0,160)      val tables  (5 x 32)
    //   [160,2200)   dense A     (5 x 17 x 24 = 2040)
    //   [2200,2285)  b vectors   (5 x 17)
    //   [2285,2305)  p_r (20)
    //   [2305,2345)  v   (40)
    float* Lb = s_h1;
    float* s_pr = Lb + 2285;
    float* s_vv = Lb + 2305;

    // ---- stage h1 + conv2 weights (float4) ----
    {
        const float4* src = (const float4*)(h1g + (size_t)b * 4000);
        float4* dst = (float4*)s_h1;
        for (int i = tid; i < 1000; i += 320) dst[i] = src[i];
        const float4* wsrc = (const float4*)cw2;
        float4* wdst = (float4*)s_w2;
        for (int i = tid; i < 1250; i += 320) wdst[i] = wsrc[i];
    }
    __syncthreads();

    // ---- conv2 + maxpool4 + relu: one pooled output per thread ----
    {
        const int oc = tid >> 4, cell = tid & 15;
        const int R0 = (cell >> 2) * 4, C0 = (cell & 3) * 4;
        float acc[16];
        #pragma unroll
        for (int i = 0; i < 16; ++i) acc[i] = 0.f;
        for (int ic = 0; ic < 10; ++ic) {
            const float* hb = &s_h1[ic * 400];
            const float* wb = &s_w2[oc * 250 + ic * 25];
            float v[8][8];
            #pragma unroll
            for (int r = 0; r < 8; ++r) {
                float4 t0 = *(const float4*)&hb[(R0 + r) * 20 + C0];
                float4 t1 = *(const float4*)&hb[(R0 + r) * 20 + C0 + 4];
                v[r][0] = t0.x; v[r][1] = t0.y; v[r][2] = t0.z; v[r][3] = t0.w;
                v[r][4] = t1.x; v[r][5] = t1.y; v[r][6] = t1.z; v[r][7] = t1.w;
            }
            #pragma unroll
            for (int k = 0; k < 5; ++k) {
                #pragma unroll
                for (int kx = 0; kx < 5; ++kx) {
                    float wv = wb[k * 5 + kx];
                    #pragma unroll
                    for (int o = 0; o < 4; ++o) {
                        #pragma unroll
                        for (int cc = 0; cc < 4; ++cc)
                            acc[o * 4 + cc] = fmaf(v[o + k][cc + kx], wv, acc[o * 4 + cc]);
                    }
                }
            }
        }
        float m = acc[0];
        #pragma unroll
        for (int i = 1; i < 16; ++i) m = fmaxf(m, acc[i]);
        s_h2[tid] = fmaxf(m + cb2[oc], 0.f);
    }
    __syncthreads();

    // ---- dense 320 -> 150, relu ----
    if (tid < 150) {
        const float* w = w3 + tid * 320;
        float a0 = b3[tid], a1 = 0.f, a2 = 0.f, a3 = 0.f;
        for (int k = 0; k < 320; k += 4) {
            a0 = fmaf(s_h2[k],     w[k],     a0);
            a1 = fmaf(s_h2[k + 1], w[k + 1], a1);
            a2 = fmaf(s_h2[k + 2], w[k + 2], a2);
            a3 = fmaf(s_h2[k + 3], w[k + 3], a3);
        }
        s_t1[tid] = fmaxf((a0 + a1) + (a2 + a3), 0.f);
    }
    __syncthreads();

    if (tid < 100) {
        const float* w = w4 + tid * 150;
        float a0 = b4[tid], a1 = 0.f;
        for (int k = 0; k < 150; k += 2) {
            a0 = fmaf(s_t1[k],     w[k],     a0);
            a1 = fmaf(s_t1[k + 1], w[k + 1], a1);
        }
        s_hc[tid] = fmaxf(a0 + a1, 0.f);
    }
    if (tid >= 100 && tid < 145) s_hc[tid] = xtraj[b * 45 + (tid - 100)];
    __syncthreads();

    if (tid < 100) {
        const float* w = pw1 + tid * 145;
        float acc = pb1[tid];
        for (int k = 0; k < 145; ++k) acc = fmaf(s_hc[k], w[k], acc);
        s_m1[tid] = fmaxf(acc, 0.f);
    } else if (tid >= 128 && tid < 228) {
        int i = tid - 128;
        const float* w = vw1 + i * 145;
        float acc = vb1[i];
        for (int k = 0; k < 145; ++k) acc = fmaf(s_hc[k], w[k], acc);
        s_m1[tid] = fmaxf(acc, 0.f);
    }
    __syncthreads();

    if (tid < 100) {
        const float* w = pw2 + tid * 100;
        float acc = pb2[tid];
        for (int k = 0; k < 100; ++k) acc = fmaf(s_m1[k], w[k], acc);
        s_m2[tid] = fmaxf(acc, 0.f);
    } else if (tid >= 128 && tid < 228) {
        int i = tid - 128;
        const float* w = vw2 + i * 100;
        float acc = vb2[i];
        for (int k = 0; k < 100; ++k) acc = fmaf(s_m1[128 + k], w[k], acc);
        s_m2[tid] = fmaxf(acc, 0.f);
    }
    __syncthreads();

    if (tid < 20) {
        const float* w = pw3 + tid * 100;
        float acc = pb3[tid];
        for (int k = 0; k < 100; ++k) acc = fmaf(s_m2[k], w[k], acc);
        s_pr[tid] = acc;
        out[b * 100 + 40 + tid] = 1000.f * (acc - x[b * 160 + tid]);
    } else if (tid >= 128 && tid < 168) {
        int i = tid - 128;
        const float* w = vw3 + i * 100;
        float acc = vb3[i];
        for (int k = 0; k < 100; ++k) acc = fmaf(s_m2[128 + k], w[k], acc);
        s_vv[i] = acc;
        out[b * 100 + 60 + i] = 1000.f * (acc - x[b * 160 + 120 + i]);
    }
    __syncthreads();

    // =========================== LP phase ==================================
    if (tid >= 160) return;
    const int t = tid >> 5;          // time index 0..4  (= problem within sample)
    const int l = tid & 31;          // lane within problem
    const float* xt = xtraj + b * 45;
    const float* xb = x + b * 160;

    float* val = Lb + t * 32;
    float* Ag  = Lb + 160 + t * 408;     // dense A [17][24]
    float* bg  = Lb + 2200 + t * 17;

    // ---- value table ----
    {
        float v_ = 0.f;
        if (l == 1) v_ = 1.f;
        else if (l == 2) v_ = -1.f;
        else if (l >= 3 && l <= 10) {
            float r0 = xt[t], r1 = xt[5 + t];
            switch (l) {
                case 3:  v_ = r1 - s_pr[10 + t]; break;
                case 4:  v_ = r1 - s_pr[15 + t]; break;
                case 5:  v_ = s_pr[0 + t] - r0;  break;
                case 6:  v_ = s_pr[5 + t] - r0;  break;
                case 7:  v_ = r1 - xb[60 + 10 + t]; break;
                case 8:  v_ = r1 - xb[60 + 15 + t]; break;
                case 9:  v_ = xb[60 + 0 + t] - r0;  break;
                default: v_ = xb[60 + 5 + t] - r0;  break;
            }
        }
        else if (l >= 11 && l <= 16) v_ = -s_vv[5 * (l - 11) + t];
        else if (l >= 17 && l <= 22) v_ = xb[20 + 5 * (l - 17) + t];
        else if (l >= 23 && l <= 30) v_ = xb[80 + 5 * (l - 23) + t];
        val[l] = v_;
    }
    // ---- zero + build dense A, b (all intra-wave, DS in-order) ----
    for (int i = l; i < 408; i += 32) Ag[i] = 0.f;
    if (l < 17) {
        #pragma unroll
        for (int k = 0; k < 8; ++k) {
            int sel = AZ_SEL[l][k];
            if (sel != 0) Ag[l * 24 + (int)AZ_IDX[l][k]] = val[sel];
        }
        float bb = 0.f;
        if (l == 0) bb = xt[30 + t];
        else if (l == 1) bb = xt[35 + t];
        else if (l == 2) bb = xt[40 + t];
        else if (l == 5 || l == 8) bb = 1.f;
        bg[l] = bb;
    }

    // ---- numeric M-row coefficients + c = (A^T b)_l ----
    float mcf[10];
    int midx[10];
    float cc = 0.f;
    #pragma unroll
    for (int k = 0; k < 10; ++k) { mcf[k] = 0.f; midx[k] = 0; }
    if (l < 24) {
        int e0 = AT_IDX[l][0], e1 = AT_IDX[l][1], e2 = AT_IDX[l][2];
        float a0 = Ag[e0 * 24 + l], a1 = Ag[e1 * 24 + l], a2 = Ag[e2 * 24 + l];
        cc = a0 * bg[e0] + a1 * bg[e1] + a2 * bg[e2];
        #pragma unroll
        for (int k = 0; k < 10; ++k) {
            int j = M_IDX[l][k];
            midx[k] = j;
            float m = a0 * Ag[e0 * 24 + j] + a1 * Ag[e1 * 24 + j] + a2 * Ag[e2 * 24 + j];
            mcf[k] = (M_MSK[l][k] != 0) ? m : 0.f;
        }
    }

    const bool isF  = (l >= 4 && l < 8);
    const bool isNN = (l >= 12);

    // ---- spectral norm: 25 power iterations, u <- M u / ||M u|| ----
    float u = (l < 24) ? 1.f : 0.f;
    for (int it = 0; it < 25; ++it) {
        float pd[10];
        #pragma unroll
        for (int k = 0; k < 10; ++k) pd[k] = mcf[k] * __shfl(u, midx[k], 32);
        float w = (((pd[0] + pd[1]) + (pd[2] + pd[3])) + ((pd[4] + pd[5]) + (pd[6] + pd[7]))) + (pd[8] + pd[9]);
        float s = w * w;
        s += __shfl_xor(s, 16, 32); s += __shfl_xor(s, 8, 32);
        s += __shfl_xor(s, 4, 32);  s += __shfl_xor(s, 2, 32);
        s += __shfl_xor(s, 1, 32);
        u = w / (sqrtf(s) + 1e-12f);
    }
    float tau;
    {
        float pd[10];
        #pragma unroll
        for (int k = 0; k < 10; ++k) pd[k] = mcf[k] * __shfl(u, midx[k], 32);
        float w = (((pd[0] + pd[1]) + (pd[2] + pd[3])) + ((pd[4] + pd[5]) + (pd[6] + pd[7]))) + (pd[8] + pd[9]);
        float s2 = u * w;   // u^T M u = ||A u||^2
        s2 += __shfl_xor(s2, 16, 32); s2 += __shfl_xor(s2, 8, 32);
        s2 += __shfl_xor(s2, 4, 32);  s2 += __shfl_xor(s2, 2, 32);
        s2 += __shfl_xor(s2, 1, 32);
        tau = 0.9f / (sqrtf(fmaxf(s2, 0.f)) + 1e-8f);
    }

    // ---- PDHG, q-form: 400 iterations, one gather each ----
    float zv = 0.f, zbv = 0.f, qv = 0.f;
    for (int it = 0; it < 400; ++it) {
        float pd[10];
        #pragma unroll
        for (int k = 0; k < 10; ++k) pd[k] = mcf[k] * __shfl(zbv, midx[k], 32);
        float s = (((pd[0] + pd[1]) + (pd[2] + pd[3])) + ((pd[4] + pd[5]) + (pd[6] + pd[7]))) + (pd[8] + pd[9]);
        qv = fmaf(tau, s - cc, qv);

        float gg = fmaf(-tau, qv, zv);
        float cl = fminf(fmaxf(gg, -tau), tau);   // v_med3 clamp
        float st = gg - cl;                       // soft-threshold
        float nn = fmaxf(gg, 0.f);
        float zn = isF ? st : (isNN ? nn : gg);
        zbv = 2.f * zn - zv;
        zv = zn;
    }

    // ---- write p (z0..z3) and f (z4..z7) ----
    {
        float* ob = out + b * 100;
        if (l < 4)      ob[l * 5 + t]            = 100.f * zv;
        else if (l < 8) ob[20 + (l - 4) * 5 + t] = 100.f * zv;
    }
}

extern "C" void kernel_launch(void* const* d_in, const int* in_sizes, int n_in,
                              void* d_out, int out_size, void* d_ws, size_t ws_size,
                              hipStream_t stream) {
    const float* xtraj = (const float*)d_in[0];
    const float* x     = (const float*)d_in[1];
    const float* x_img = (const float*)d_in[2];
    const float* cw1 = (const float*)d_in[3];
    const float* cb1 = (const float*)d_in[4];
    const float* cw2 = (const float*)d_in[5];
    const float* cb2 = (const float*)d_in[6];
    const float* w3  = (const float*)d_in[7];
    const float* b3  = (const float*)d_in[8];
    const float* w4  = (const float*)d_in[9];
    const float* b4  = (const float*)d_in[10];
    const float* pw1 = (const float*)d_in[11];
    const float* pb1 = (const float*)d_in[12];
    const float* pw2 = (const float*)d_in[13];
    const float* pb2 = (const float*)d_in[14];
    const float* pw3 = (const float*)d_in[15];
    const float* pb3 = (const float*)d_in[16];
    const float* vw1 = (const float*)d_in[17];
    const float* vb1 = (const float*)d_in[18];
    const float* vw2 = (const float*)d_in[19];
    const float* vb2 = (const float*)d_in[20];
    const float* vw3 = (const float*)d_in[21];
    const float* vb3 = (const float*)d_in[22];

    float* out = (float*)d_out;
    const int Bn = in_sizes[0] / 45;

    float* ws_h1 = (float*)d_ws;   // Bn*4000 floats (~8.2 MB)

    conv1_kernel<<<Bn * 4, 128, 0, stream>>>(x_img, cw1, cb1, ws_h1);

    head_lp_kernel<<<Bn, 320, 0, stream>>>(
        xtraj, x, ws_h1, cw2, cb2, w3, b3, w4, b4,
        pw1, pb1, pw2, pb2, pw3, pb3, vw1, vb1, vw2, vb2, vw3, vb3,
        out);
}

// Round 7
// 267.132 us; speedup vs baseline: 1.0188x; 1.0188x over previous
//
#include <hip/hip_runtime.h>

// ---------------------------------------------------------------------------
// K1: conv1 (11x11, 50->40) + maxpool2 + relu, 4 blocks per sample.
// (unchanged)
// ---------------------------------------------------------------------------
__global__ __launch_bounds__(128) void conv1_kernel(
    const float* __restrict__ x_img, const float* __restrict__ cw1,
    const float* __restrict__ cb1, float* __restrict__ h1)
{
    const int blk = blockIdx.x;
    const int b = blk >> 2;
    const int c = blk & 3;
    const int tid = threadIdx.x;

    __shared__ __align__(16) float s_img[1000];

    const float* img = x_img + (size_t)b * 2500 + (size_t)(10 * c) * 50;
    for (int i = tid; i < 1000; i += 128) s_img[i] = img[i];
    __syncthreads();

    if (tid < 100) {
        const int ly = tid / 20, px = tid % 20;
        const int py = 5 * c + ly;
        const int C = 2 * px;
        float acc0[10], acc1[10], acc2[10], acc3[10];
        #pragma unroll
        for (int oc = 0; oc < 10; ++oc) { acc0[oc] = 0.f; acc1[oc] = 0.f; acc2[oc] = 0.f; acc3[oc] = 0.f; }
        for (int r = 0; r < 12; ++r) {
            float v[12];
            #pragma unroll
            for (int j = 0; j < 6; ++j) {
                float2 t = *(const float2*)&s_img[(2 * ly + r) * 50 + C + 2 * j];
                v[2 * j] = t.x; v[2 * j + 1] = t.y;
            }
            if (r < 11) {
                #pragma unroll
                for (int oc = 0; oc < 10; ++oc) {
                    #pragma unroll
                    for (int kx = 0; kx < 11; ++kx) {
                        float w0 = cw1[oc * 121 + r * 11 + kx];
                        acc0[oc] = fmaf(v[kx], w0, acc0[oc]);
                        acc1[oc] = fmaf(v[kx + 1], w0, acc1[oc]);
                    }
                }
            }
            if (r >= 1) {
                #pragma unroll
                for (int oc = 0; oc < 10; ++oc) {
                    #pragma unroll
                    for (int kx = 0; kx < 11; ++kx) {
                        float w1 = cw1[oc * 121 + (r - 1) * 11 + kx];
                        acc2[oc] = fmaf(v[kx], w1, acc2[oc]);
                        acc3[oc] = fmaf(v[kx + 1], w1, acc3[oc]);
                    }
                }
            }
        }
        float* hb = h1 + (size_t)b * 4000 + py * 20 + px;
        #pragma unroll
        for (int oc = 0; oc < 10; ++oc) {
            float m = fmaxf(fmaxf(acc0[oc], acc1[oc]), fmaxf(acc2[oc], acc3[oc]));
            hb[oc * 400] = fmaxf(m + cb1[oc], 0.f);
        }
    }
}

// ---------------------------------------------------------------------------
// LP structure tables (verified rounds 3-6).
// ---------------------------------------------------------------------------
__device__ const signed char AZ_IDX[32][8] = {
    {4,5,6,7,8,9,0,0},{10,11,0,0,0,0,0,0},{4,5,6,7,8,9,10,11},
    {0,12,14,0,0,0,0,0},{2,12,14,0,0,0,0,0},{12,14,0,0,0,0,0,0},
    {1,13,15,0,0,0,0,0},{3,13,15,0,0,0,0,0},{13,15,0,0,0,0,0,0},
    {16,18,4,0,0,0,0,0},{16,18,6,0,0,0,0,0},{17,19,5,0,0,0,0,0},
    {17,19,7,0,0,0,0,0},{20,21,8,0,0,0,0,0},{20,21,10,0,0,0,0,0},
    {22,23,9,0,0,0,0,0},{22,23,11,0,0,0,0,0},
    {0},{0},{0},{0},{0},{0},{0},{0},{0},{0},{0},{0},{0},{0},{0}
};
__device__ const signed char AZ_SEL[32][8] = {
    {1,1,1,1,1,1,0,0},{1,1,0,0,0,0,0,0},{3,4,5,6,7,8,9,10},
    {1,11,13,0,0,0,0,0},{1,12,14,0,0,0,0,0},{1,1,0,0,0,0,0,0},
    {1,13,15,0,0,0,0,0},{1,14,16,0,0,0,0,0},{1,1,0,0,0,0,0,0},
    {17,19,2,0,0,0,0,0},{18,20,2,0,0,0,0,0},{19,21,2,0,0,0,0,0},
    {20,22,2,0,0,0,0,0},{23,25,2,0,0,0,0,0},{24,26,2,0,0,0,0,0},
    {27,29,2,0,0,0,0,0},{28,30,2,0,0,0,0,0},
    {0},{0},{0},{0},{0},{0},{0},{0},{0},{0},{0},{0},{0},{0},{0}
};
__device__ const signed char AT_IDX[32][3] = {
    {3,0,0},{6,0,0},{4,0,0},{7,0,0},
    {0,2,9},{0,2,11},{0,2,10},{0,2,12},{0,2,13},{0,2,15},{1,2,14},{1,2,16},
    {3,4,5},{6,7,8},{3,4,5},{6,7,8},
    {9,10,0},{11,12,0},{9,10,0},{11,12,0},
    {13,14,0},{13,14,0},{15,16,0},{15,16,0},
    {0},{0},{0},{0},{0},{0},{0},{0}
};
__device__ const signed char M_IDX[32][10] = {
    {0,12,14,0,0,0,0,0,0,0},
    {1,13,15,0,0,0,0,0,0,0},
    {2,12,14,0,0,0,0,0,0,0},
    {3,13,15,0,0,0,0,0,0,0},
    {4,5,6,7,8,9,10,11,16,18},
    {4,5,6,7,8,9,10,11,17,19},
    {4,5,6,7,8,9,10,11,16,18},
    {4,5,6,7,8,9,10,11,17,19},
    {4,5,6,7,8,9,10,11,20,21},
    {4,5,6,7,8,9,10,11,22,23},
    {4,5,6,7,8,9,10,11,20,21},
    {4,5,6,7,8,9,10,11,22,23},
    {0,2,12,14,0,0,0,0,0,0},
    {1,3,13,15,0,0,0,0,0,0},
    {0,2,12,14,0,0,0,0,0,0},
    {1,3,13,15,0,0,0,0,0,0},
    {4,6,16,18,0,0,0,0,0,0},
    {5,7,17,19,0,0,0,0,0,0},
    {4,6,16,18,0,0,0,0,0,0},
    {5,7,17,19,0,0,0,0,0,0},
    {8,10,20,21,0,0,0,0,0,0},
    {8,10,20,21,0,0,0,0,0,0},
    {9,11,22,23,0,0,0,0,0,0},
    {9,11,22,23,0,0,0,0,0,0},
    {0},{0},{0},{0},{0},{0},{0},{0}
};
__device__ const signed char M_MSK[32][10] = {
    {1,1,1,0,0,0,0,0,0,0},
    {1,1,1,0,0,0,0,0,0,0},
    {1,1,1,0,0,0,0,0,0,0},
    {1,1,1,0,0,0,0,0,0,0},
    {1,1,1,1,1,1,1,1,1,1},
    {1,1,1,1,1,1,1,1,1,1},
    {1,1,1,1,1,1,1,1,1,1},
    {1,1,1,1,1,1,1,1,1,1},
    {1,1,1,1,1,1,1,1,1,1},
    {1,1,1,1,1,1,1,1,1,1},
    {1,1,1,1,1,1,1,1,1,1},
    {1,1,1,1,1,1,1,1,1,1},
    {1,1,1,1,0,0,0,0,0,0},
    {1,1,1,1,0,0,0,0,0,0},
    {1,1,1,1,0,0,0,0,0,0},
    {1,1,1,1,0,0,0,0,0,0},
    {1,1,1,1,0,0,0,0,0,0},
    {1,1,1,1,0,0,0,0,0,0},
    {1,1,1,1,0,0,0,0,0,0},
    {1,1,1,1,0,0,0,0,0,0},
    {1,1,1,1,0,0,0,0,0,0},
    {1,1,1,1,0,0,0,0,0,0},
    {1,1,1,1,0,0,0,0,0,0},
    {1,1,1,1,0,0,0,0,0,0},
    {0},{0},{0},{0},{0},{0},{0},{0}
};

// Gather helper: raw wave64 bpermute with precomputed byte address.
__device__ __forceinline__ float bperm(int addr, float v) {
    return __int_as_float(__builtin_amdgcn_ds_bpermute(addr, __float_as_int(v)));
}

// ---------------------------------------------------------------------------
// K2: head (conv2 + dense + MLPs) fused with the 5 per-t LP solves.
// LP loop: raw bpermute (hoisted addresses), tau^2-prescaled normal-equation
// form, power iteration normalized every 5 steps.
// ---------------------------------------------------------------------------
__global__ __launch_bounds__(320) void head_lp_kernel(
    const float* __restrict__ xtraj, const float* __restrict__ x,
    const float* __restrict__ h1g,
    const float* __restrict__ cw2, const float* __restrict__ cb2,
    const float* __restrict__ w3, const float* __restrict__ b3,
    const float* __restrict__ w4, const float* __restrict__ b4,
    const float* __restrict__ pw1, const float* __restrict__ pb1,
    const float* __restrict__ pw2, const float* __restrict__ pb2,
    const float* __restrict__ pw3, const float* __restrict__ pb3,
    const float* __restrict__ vw1, const float* __restrict__ vb1,
    const float* __restrict__ vw2, const float* __restrict__ vb2,
    const float* __restrict__ vw3, const float* __restrict__ vb3,
    float* __restrict__ out)
{
    const int b = blockIdx.x;
    const int tid = threadIdx.x;

    __shared__ __align__(16) float s_h1[4000];   // conv2 input; later LP scratch
    __shared__ __align__(16) float s_w2[5000];
    __shared__ __align__(16) float s_h2[320];
    __shared__ float s_hc[145];
    __shared__ float s_t1[152];
    __shared__ float s_m1[256];
    __shared__ float s_m2[256];

    float* Lb = s_h1;
    float* s_pr = Lb + 2285;
    float* s_vv = Lb + 2305;

    // ---- stage h1 + conv2 weights (float4) ----
    {
        const float4* src = (const float4*)(h1g + (size_t)b * 4000);
        float4* dst = (float4*)s_h1;
        for (int i = tid; i < 1000; i += 320) dst[i] = src[i];
        const float4* wsrc = (const float4*)cw2;
        float4* wdst = (float4*)s_w2;
        for (int i = tid; i < 1250; i += 320) wdst[i] = wsrc[i];
    }
    __syncthreads();

    // ---- conv2 + maxpool4 + relu ----
    {
        const int oc = tid >> 4, cell = tid & 15;
        const int R0 = (cell >> 2) * 4, C0 = (cell & 3) * 4;
        float acc[16];
        #pragma unroll
        for (int i = 0; i < 16; ++i) acc[i] = 0.f;
        for (int ic = 0; ic < 10; ++ic) {
            const float* hb = &s_h1[ic * 400];
            const float* wb = &s_w2[oc * 250 + ic * 25];
            float v[8][8];
            #pragma unroll
            for (int r = 0; r < 8; ++r) {
                float4 t0 = *(const float4*)&hb[(R0 + r) * 20 + C0];
                float4 t1 = *(const float4*)&hb[(R0 + r) * 20 + C0 + 4];
                v[r][0] = t0.x; v[r][1] = t0.y; v[r][2] = t0.z; v[r][3] = t0.w;
                v[r][4] = t1.x; v[r][5] = t1.y; v[r][6] = t1.z; v[r][7] = t1.w;
            }
            #pragma unroll
            for (int k = 0; k < 5; ++k) {
                #pragma unroll
                for (int kx = 0; kx < 5; ++kx) {
                    float wv = wb[k * 5 + kx];
                    #pragma unroll
                    for (int o = 0; o < 4; ++o) {
                        #pragma unroll
                        for (int cc = 0; cc < 4; ++cc)
                            acc[o * 4 + cc] = fmaf(v[o + k][cc + kx], wv, acc[o * 4 + cc]);
                    }
                }
            }
        }
        float m = acc[0];
        #pragma unroll
        for (int i = 1; i < 16; ++i) m = fmaxf(m, acc[i]);
        s_h2[tid] = fmaxf(m + cb2[oc], 0.f);
    }
    __syncthreads();

    if (tid < 150) {
        const float* w = w3 + tid * 320;
        float a0 = b3[tid], a1 = 0.f, a2 = 0.f, a3 = 0.f;
        for (int k = 0; k < 320; k += 4) {
            a0 = fmaf(s_h2[k],     w[k],     a0);
            a1 = fmaf(s_h2[k + 1], w[k + 1], a1);
            a2 = fmaf(s_h2[k + 2], w[k + 2], a2);
            a3 = fmaf(s_h2[k + 3], w[k + 3], a3);
        }
        s_t1[tid] = fmaxf((a0 + a1) + (a2 + a3), 0.f);
    }
    __syncthreads();

    if (tid < 100) {
        const float* w = w4 + tid * 150;
        float a0 = b4[tid], a1 = 0.f;
        for (int k = 0; k < 150; k += 2) {
            a0 = fmaf(s_t1[k],     w[k],     a0);
            a1 = fmaf(s_t1[k + 1], w[k + 1], a1);
        }
        s_hc[tid] = fmaxf(a0 + a1, 0.f);
    }
    if (tid >= 100 && tid < 145) s_hc[tid] = xtraj[b * 45 + (tid - 100)];
    __syncthreads();

    if (tid < 100) {
        const float* w = pw1 + tid * 145;
        float acc = pb1[tid];
        for (int k = 0; k < 145; ++k) acc = fmaf(s_hc[k], w[k], acc);
        s_m1[tid] = fmaxf(acc, 0.f);
    } else if (tid >= 128 && tid < 228) {
        int i = tid - 128;
        const float* w = vw1 + i * 145;
        float acc = vb1[i];
        for (int k = 0; k < 145; ++k) acc = fmaf(s_hc[k], w[k], acc);
        s_m1[tid] = fmaxf(acc, 0.f);
    }
    __syncthreads();

    if (tid < 100) {
        const float* w = pw2 + tid * 100;
        float acc = pb2[tid];
        for (int k = 0; k < 100; ++k) acc = fmaf(s_m1[k], w[k], acc);
        s_m2[tid] = fmaxf(acc, 0.f);
    } else if (tid >= 128 && tid < 228) {
        int i = tid - 128;
        const float* w = vw2 + i * 100;
        float acc = vb2[i];
        for (int k = 0; k < 100; ++k) acc = fmaf(s_m1[128 + k], w[k], acc);
        s_m2[tid] = fmaxf(acc, 0.f);
    }
    __syncthreads();

    if (tid < 20) {
        const float* w = pw3 + tid * 100;
        float acc = pb3[tid];
        for (int k = 0; k < 100; ++k) acc = fmaf(s_m2[k], w[k], acc);
        s_pr[tid] = acc;
        out[b * 100 + 40 + tid] = 1000.f * (acc - x[b * 160 + tid]);
    } else if (tid >= 128 && tid < 168) {
        int i = tid - 128;
        const float* w = vw3 + i * 100;
        float acc = vb3[i];
        for (int k = 0; k < 100; ++k) acc = fmaf(s_m2[128 + k], w[k], acc);
        s_vv[i] = acc;
        out[b * 100 + 60 + i] = 1000.f * (acc - x[b * 160 + 120 + i]);
    }
    __syncthreads();

    // =========================== LP phase ==================================
    if (tid >= 160) return;
    const int t = tid >> 5;
    const int l = tid & 31;
    const float* xt = xtraj + b * 45;
    const float* xb = x + b * 160;

    float* val = Lb + t * 32;
    float* Ag  = Lb + 160 + t * 408;
    float* bg  = Lb + 2200 + t * 17;

    // ---- value table ----
    {
        float v_ = 0.f;
        if (l == 1) v_ = 1.f;
        else if (l == 2) v_ = -1.f;
        else if (l >= 3 && l <= 10) {
            float r0 = xt[t], r1 = xt[5 + t];
            switch (l) {
                case 3:  v_ = r1 - s_pr[10 + t]; break;
                case 4:  v_ = r1 - s_pr[15 + t]; break;
                case 5:  v_ = s_pr[0 + t] - r0;  break;
                case 6:  v_ = s_pr[5 + t] - r0;  break;
                case 7:  v_ = r1 - xb[60 + 10 + t]; break;
                case 8:  v_ = r1 - xb[60 + 15 + t]; break;
                case 9:  v_ = xb[60 + 0 + t] - r0;  break;
                default: v_ = xb[60 + 5 + t] - r0;  break;
            }
        }
        else if (l >= 11 && l <= 16) v_ = -s_vv[5 * (l - 11) + t];
        else if (l >= 17 && l <= 22) v_ = xb[20 + 5 * (l - 17) + t];
        else if (l >= 23 && l <= 30) v_ = xb[80 + 5 * (l - 23) + t];
        val[l] = v_;
    }
    // ---- build dense A, b (intra-wave, DS in-order) ----
    for (int i = l; i < 408; i += 32) Ag[i] = 0.f;
    if (l < 17) {
        #pragma unroll
        for (int k = 0; k < 8; ++k) {
            int sel = AZ_SEL[l][k];
            if (sel != 0) Ag[l * 24 + (int)AZ_IDX[l][k]] = val[sel];
        }
        float bb = 0.f;
        if (l == 0) bb = xt[30 + t];
        else if (l == 1) bb = xt[35 + t];
        else if (l == 2) bb = xt[40 + t];
        else if (l == 5 || l == 8) bb = 1.f;
        bg[l] = bb;
    }

    // ---- numeric M-row coefficients + c = (A^T b)_l + bpermute addresses ----
    float mcf[10];
    int adr[10];
    float cc = 0.f;
    const int base32 = (tid & 32);
    #pragma unroll
    for (int k = 0; k < 10; ++k) { mcf[k] = 0.f; adr[k] = base32 << 2; }
    if (l < 24) {
        int e0 = AT_IDX[l][0], e1 = AT_IDX[l][1], e2 = AT_IDX[l][2];
        float a0 = Ag[e0 * 24 + l], a1 = Ag[e1 * 24 + l], a2 = Ag[e2 * 24 + l];
        cc = a0 * bg[e0] + a1 * bg[e1] + a2 * bg[e2];
        #pragma unroll
        for (int k = 0; k < 10; ++k) {
            int j = M_IDX[l][k];
            adr[k] = (base32 | j) << 2;
            float m = a0 * Ag[e0 * 24 + j] + a1 * Ag[e1 * 24 + j] + a2 * Ag[e2 * 24 + j];
            mcf[k] = (M_MSK[l][k] != 0) ? m : 0.f;
        }
    }

    const bool isF  = (l >= 4 && l < 8);
    const bool isNN = (l >= 12);

    // ---- spectral norm: 25 M-applications, normalize every 5 ----
    float u = (l < 24) ? 1.f : 0.f;
    #pragma unroll 1
    for (int o = 0; o < 5; ++o) {
        #pragma unroll 1
        for (int ii = 0; ii < 5; ++ii) {
            float pd[10];
            #pragma unroll
            for (int k = 0; k < 10; ++k) pd[k] = mcf[k] * bperm(adr[k], u);
            u = (((pd[0] + pd[1]) + (pd[2] + pd[3])) + ((pd[4] + pd[5]) + (pd[6] + pd[7]))) + (pd[8] + pd[9]);
        }
        float s = u * u;
        s += __shfl_xor(s, 16, 32); s += __shfl_xor(s, 8, 32);
        s += __shfl_xor(s, 4, 32);  s += __shfl_xor(s, 2, 32);
        s += __shfl_xor(s, 1, 32);
        u = u / (sqrtf(s) + 1e-12f);
    }
    float tau;
    {
        float pd[10];
        #pragma unroll
        for (int k = 0; k < 10; ++k) pd[k] = mcf[k] * bperm(adr[k], u);
        float w = (((pd[0] + pd[1]) + (pd[2] + pd[3])) + ((pd[4] + pd[5]) + (pd[6] + pd[7]))) + (pd[8] + pd[9]);
        float s2 = u * w;   // u^T M u = ||A u||^2
        s2 += __shfl_xor(s2, 16, 32); s2 += __shfl_xor(s2, 8, 32);
        s2 += __shfl_xor(s2, 4, 32);  s2 += __shfl_xor(s2, 2, 32);
        s2 += __shfl_xor(s2, 1, 32);
        tau = 0.9f / (sqrtf(fmaxf(s2, 0.f)) + 1e-8f);
    }

    // ---- prescale by tau^2: Q = tau*q;  Q += (t2*M)zb - t2*c;  g = z - Q ----
    const float t2 = tau * tau;
    #pragma unroll
    for (int k = 0; k < 10; ++k) mcf[k] *= t2;
    const float cc2 = cc * t2;

    float zv = 0.f, zbv = 0.f, Q = 0.f;
    #pragma unroll 1
    for (int it = 0; it < 400; ++it) {
        float pd[10];
        #pragma unroll
        for (int k = 0; k < 10; ++k) pd[k] = bperm(adr[k], zbv);
        float Qm = Q - cc2;                       // overlaps bpermute wait
        #pragma unroll
        for (int k = 0; k < 10; ++k) pd[k] *= mcf[k];
        float s = (((pd[0] + pd[1]) + (pd[2] + pd[3])) + ((pd[4] + pd[5]) + (pd[6] + pd[7]))) + (pd[8] + pd[9]);
        Q = Qm + s;

        float gg = zv - Q;
        float cl = fminf(fmaxf(gg, -tau), tau);   // med3 clamp
        float st = gg - cl;                       // soft-threshold
        float nn = fmaxf(gg, 0.f);
        float zn = isF ? st : (isNN ? nn : gg);
        zbv = fmaf(2.f, zn, -zv);
        zv = zn;
    }

    // ---- write p (z0..z3) and f (z4..z7) ----
    {
        float* ob = out + b * 100;
        if (l < 4)      ob[l * 5 + t]            = 100.f * zv;
        else if (l < 8) ob[20 + (l - 4) * 5 + t] = 100.f * zv;
    }
}

extern "C" void kernel_launch(void* const* d_in, const int* in_sizes, int n_in,
                              void* d_out, int out_size, void* d_ws, size_t ws_size,
                              hipStream_t stream) {
    const float* xtraj = (const float*)d_in[0];
    const float* x     = (const float*)d_in[1];
    const float* x_img = (const float*)d_in[2];
    const float* cw1 = (const float*)d_in[3];
    const float* cb1 = (const float*)d_in[4];
    const float* cw2 = (const float*)d_in[5];
    const float* cb2 = (const float*)d_in[6];
    const float* w3  = (const float*)d_in[7];
    const float* b3  = (const float*)d_in[8];
    const float* w4  = (const float*)d_in[9];
    const float* b4  = (const float*)d_in[10];
    const float* pw1 = (const float*)d_in[11];
    const float* pb1 = (const float*)d_in[12];
    const float* pw2 = (const float*)d_in[13];
    const float* pb2 = (const float*)d_in[14];
    const float* pw3 = (const float*)d_in[15];
    const float* pb3 = (const float*)d_in[16];
    const float* vw1 = (const float*)d_in[17];
    const float* vb1 = (const float*)d_in[18];
    const float* vw2 = (const float*)d_in[19];
    const float* vb2 = (const float*)d_in[20];
    const float* vw3 = (const float*)d_in[21];
    const float* vb3 = (const float*)d_in[22];

    float* out = (float*)d_out;
    const int Bn = in_sizes[0] / 45;

    float* ws_h1 = (float*)d_ws;   // Bn*4000 floats (~8.2 MB)

    conv1_kernel<<<Bn * 4, 128, 0, stream>>>(x_img, cw1, cb1, ws_h1);

    head_lp_kernel<<<Bn, 320, 0, stream>>>(
        xtraj, x, ws_h1, cw2, cb2, w3, b3, w4, b4,
        pw1, pb1, pw2, pb2, pw3, pb3, vw1, vb1, vw2, vb2, vw3, vb3,
        out);
}

// Round 8
// 242.704 us; speedup vs baseline: 1.1214x; 1.1006x over previous
//
#include <hip/hip_runtime.h>

// ---------------------------------------------------------------------------
// K1: conv1 (11x11, 50->40) + maxpool2 + relu, 4 blocks per sample.
// (unchanged)
// ---------------------------------------------------------------------------
__global__ __launch_bounds__(128) void conv1_kernel(
    const float* __restrict__ x_img, const float* __restrict__ cw1,
    const float* __restrict__ cb1, float* __restrict__ h1)
{
    const int blk = blockIdx.x;
    const int b = blk >> 2;
    const int c = blk & 3;
    const int tid = threadIdx.x;

    __shared__ __align__(16) float s_img[1000];

    const float* img = x_img + (size_t)b * 2500 + (size_t)(10 * c) * 50;
    for (int i = tid; i < 1000; i += 128) s_img[i] = img[i];
    __syncthreads();

    if (tid < 100) {
        const int ly = tid / 20, px = tid % 20;
        const int py = 5 * c + ly;
        const int C = 2 * px;
        float acc0[10], acc1[10], acc2[10], acc3[10];
        #pragma unroll
        for (int oc = 0; oc < 10; ++oc) { acc0[oc] = 0.f; acc1[oc] = 0.f; acc2[oc] = 0.f; acc3[oc] = 0.f; }
        for (int r = 0; r < 12; ++r) {
            float v[12];
            #pragma unroll
            for (int j = 0; j < 6; ++j) {
                float2 t = *(const float2*)&s_img[(2 * ly + r) * 50 + C + 2 * j];
                v[2 * j] = t.x; v[2 * j + 1] = t.y;
            }
            if (r < 11) {
                #pragma unroll
                for (int oc = 0; oc < 10; ++oc) {
                    #pragma unroll
                    for (int kx = 0; kx < 11; ++kx) {
                        float w0 = cw1[oc * 121 + r * 11 + kx];
                        acc0[oc] = fmaf(v[kx], w0, acc0[oc]);
                        acc1[oc] = fmaf(v[kx + 1], w0, acc1[oc]);
                    }
                }
            }
            if (r >= 1) {
                #pragma unroll
                for (int oc = 0; oc < 10; ++oc) {
                    #pragma unroll
                    for (int kx = 0; kx < 11; ++kx) {
                        float w1 = cw1[oc * 121 + (r - 1) * 11 + kx];
                        acc2[oc] = fmaf(v[kx], w1, acc2[oc]);
                        acc3[oc] = fmaf(v[kx + 1], w1, acc3[oc]);
                    }
                }
            }
        }
        float* hb = h1 + (size_t)b * 4000 + py * 20 + px;
        #pragma unroll
        for (int oc = 0; oc < 10; ++oc) {
            float m = fmaxf(fmaxf(acc0[oc], acc1[oc]), fmaxf(acc2[oc], acc3[oc]));
            hb[oc * 400] = fmaxf(m + cb1[oc], 0.f);
        }
    }
}

// ---------------------------------------------------------------------------
// LP structure tables (verified rounds 3-7).
// ---------------------------------------------------------------------------
__device__ const signed char AZ_IDX[32][8] = {
    {4,5,6,7,8,9,0,0},{10,11,0,0,0,0,0,0},{4,5,6,7,8,9,10,11},
    {0,12,14,0,0,0,0,0},{2,12,14,0,0,0,0,0},{12,14,0,0,0,0,0,0},
    {1,13,15,0,0,0,0,0},{3,13,15,0,0,0,0,0},{13,15,0,0,0,0,0,0},
    {16,18,4,0,0,0,0,0},{16,18,6,0,0,0,0,0},{17,19,5,0,0,0,0,0},
    {17,19,7,0,0,0,0,0},{20,21,8,0,0,0,0,0},{20,21,10,0,0,0,0,0},
    {22,23,9,0,0,0,0,0},{22,23,11,0,0,0,0,0},
    {0},{0},{0},{0},{0},{0},{0},{0},{0},{0},{0},{0},{0},{0},{0}
};
__device__ const signed char AZ_SEL[32][8] = {
    {1,1,1,1,1,1,0,0},{1,1,0,0,0,0,0,0},{3,4,5,6,7,8,9,10},
    {1,11,13,0,0,0,0,0},{1,12,14,0,0,0,0,0},{1,1,0,0,0,0,0,0},
    {1,13,15,0,0,0,0,0},{1,14,16,0,0,0,0,0},{1,1,0,0,0,0,0,0},
    {17,19,2,0,0,0,0,0},{18,20,2,0,0,0,0,0},{19,21,2,0,0,0,0,0},
    {20,22,2,0,0,0,0,0},{23,25,2,0,0,0,0,0},{24,26,2,0,0,0,0,0},
    {27,29,2,0,0,0,0,0},{28,30,2,0,0,0,0,0},
    {0},{0},{0},{0},{0},{0},{0},{0},{0},{0},{0},{0},{0},{0},{0}
};
__device__ const signed char AT_IDX[32][3] = {
    {3,0,0},{6,0,0},{4,0,0},{7,0,0},
    {0,2,9},{0,2,11},{0,2,10},{0,2,12},{0,2,13},{0,2,15},{1,2,14},{1,2,16},
    {3,4,5},{6,7,8},{3,4,5},{6,7,8},
    {9,10,0},{11,12,0},{9,10,0},{11,12,0},
    {13,14,0},{13,14,0},{15,16,0},{15,16,0},
    {0},{0},{0},{0},{0},{0},{0},{0}
};
// Window bases for the 3 float4 mailbox reads (cover all M-row supports).
__device__ const signed char WBA[32] = {0,0,0,0, 4,4,4,4, 4,4,4,4, 0,0,0,0, 4,4,4,4, 8,8,8,8, 0,0,0,0,0,0,0,0};
__device__ const signed char WBB[32] = {12,12,12,12, 8,8,8,8, 8,8,8,8, 12,12,12,12, 16,16,16,16, 20,20,20,20, 0,0,0,0,0,0,0,0};
__device__ const signed char WBC[32] = {0,0,0,0, 16,16,16,16, 20,20,20,20, 0,0,0,0, 0,0,0,0, 0,0,0,0, 0,0,0,0,0,0,0,0};

// ---------------------------------------------------------------------------
// K2: head (conv2 + dense + MLPs) fused with the 5 per-t LP solves.
// LP loop: LDS mailbox — 1 ds_write_b32 + 3 ds_read_b128 per iteration
// (was 10 ds_bpermute). M = A^T A coefficients for the 12 window slots are
// computed numerically at setup (structural zeros fall out exactly).
// ---------------------------------------------------------------------------
__global__ __launch_bounds__(320) void head_lp_kernel(
    const float* __restrict__ xtraj, const float* __restrict__ x,
    const float* __restrict__ h1g,
    const float* __restrict__ cw2, const float* __restrict__ cb2,
    const float* __restrict__ w3, const float* __restrict__ b3,
    const float* __restrict__ w4, const float* __restrict__ b4,
    const float* __restrict__ pw1, const float* __restrict__ pb1,
    const float* __restrict__ pw2, const float* __restrict__ pb2,
    const float* __restrict__ pw3, const float* __restrict__ pb3,
    const float* __restrict__ vw1, const float* __restrict__ vb1,
    const float* __restrict__ vw2, const float* __restrict__ vb2,
    const float* __restrict__ vw3, const float* __restrict__ vb3,
    float* __restrict__ out)
{
    const int b = blockIdx.x;
    const int tid = threadIdx.x;

    __shared__ __align__(16) float s_h1[4000];   // conv2 input; later LP scratch
    __shared__ __align__(16) float s_w2[5000];
    __shared__ __align__(16) float s_h2[320];
    __shared__ float s_hc[145];
    __shared__ float s_t1[152];
    __shared__ float s_m1[256];
    __shared__ float s_m2[256];

    float* Lb = s_h1;
    float* s_pr = Lb + 2285;
    float* s_vv = Lb + 2305;

    // ---- stage h1 + conv2 weights (float4) ----
    {
        const float4* src = (const float4*)(h1g + (size_t)b * 4000);
        float4* dst = (float4*)s_h1;
        for (int i = tid; i < 1000; i += 320) dst[i] = src[i];
        const float4* wsrc = (const float4*)cw2;
        float4* wdst = (float4*)s_w2;
        for (int i = tid; i < 1250; i += 320) wdst[i] = wsrc[i];
    }
    __syncthreads();

    // ---- conv2 + maxpool4 + relu ----
    {
        const int oc = tid >> 4, cell = tid & 15;
        const int R0 = (cell >> 2) * 4, C0 = (cell & 3) * 4;
        float acc[16];
        #pragma unroll
        for (int i = 0; i < 16; ++i) acc[i] = 0.f;
        for (int ic = 0; ic < 10; ++ic) {
            const float* hb = &s_h1[ic * 400];
            const float* wb = &s_w2[oc * 250 + ic * 25];
            float v[8][8];
            #pragma unroll
            for (int r = 0; r < 8; ++r) {
                float4 t0 = *(const float4*)&hb[(R0 + r) * 20 + C0];
                float4 t1 = *(const float4*)&hb[(R0 + r) * 20 + C0 + 4];
                v[r][0] = t0.x; v[r][1] = t0.y; v[r][2] = t0.z; v[r][3] = t0.w;
                v[r][4] = t1.x; v[r][5] = t1.y; v[r][6] = t1.z; v[r][7] = t1.w;
            }
            #pragma unroll
            for (int k = 0; k < 5; ++k) {
                #pragma unroll
                for (int kx = 0; kx < 5; ++kx) {
                    float wv = wb[k * 5 + kx];
                    #pragma unroll
                    for (int o = 0; o < 4; ++o) {
                        #pragma unroll
                        for (int cc = 0; cc < 4; ++cc)
                            acc[o * 4 + cc] = fmaf(v[o + k][cc + kx], wv, acc[o * 4 + cc]);
                    }
                }
            }
        }
        float m = acc[0];
        #pragma unroll
        for (int i = 1; i < 16; ++i) m = fmaxf(m, acc[i]);
        s_h2[tid] = fmaxf(m + cb2[oc], 0.f);
    }
    __syncthreads();

    if (tid < 150) {
        const float* w = w3 + tid * 320;
        float a0 = b3[tid], a1 = 0.f, a2 = 0.f, a3 = 0.f;
        for (int k = 0; k < 320; k += 4) {
            a0 = fmaf(s_h2[k],     w[k],     a0);
            a1 = fmaf(s_h2[k + 1], w[k + 1], a1);
            a2 = fmaf(s_h2[k + 2], w[k + 2], a2);
            a3 = fmaf(s_h2[k + 3], w[k + 3], a3);
        }
        s_t1[tid] = fmaxf((a0 + a1) + (a2 + a3), 0.f);
    }
    __syncthreads();

    if (tid < 100) {
        const float* w = w4 + tid * 150;
        float a0 = b4[tid], a1 = 0.f;
        for (int k = 0; k < 150; k += 2) {
            a0 = fmaf(s_t1[k],     w[k],     a0);
            a1 = fmaf(s_t1[k + 1], w[k + 1], a1);
        }
        s_hc[tid] = fmaxf(a0 + a1, 0.f);
    }
    if (tid >= 100 && tid < 145) s_hc[tid] = xtraj[b * 45 + (tid - 100)];
    __syncthreads();

    if (tid < 100) {
        const float* w = pw1 + tid * 145;
        float acc = pb1[tid];
        for (int k = 0; k < 145; ++k) acc = fmaf(s_hc[k], w[k], acc);
        s_m1[tid] = fmaxf(acc, 0.f);
    } else if (tid >= 128 && tid < 228) {
        int i = tid - 128;
        const float* w = vw1 + i * 145;
        float acc = vb1[i];
        for (int k = 0; k < 145; ++k) acc = fmaf(s_hc[k], w[k], acc);
        s_m1[tid] = fmaxf(acc, 0.f);
    }
    __syncthreads();

    if (tid < 100) {
        const float* w = pw2 + tid * 100;
        float acc = pb2[tid];
        for (int k = 0; k < 100; ++k) acc = fmaf(s_m1[k], w[k], acc);
        s_m2[tid] = fmaxf(acc, 0.f);
    } else if (tid >= 128 && tid < 228) {
        int i = tid - 128;
        const float* w = vw2 + i * 100;
        float acc = vb2[i];
        for (int k = 0; k < 100; ++k) acc = fmaf(s_m1[128 + k], w[k], acc);
        s_m2[tid] = fmaxf(acc, 0.f);
    }
    __syncthreads();

    if (tid < 20) {
        const float* w = pw3 + tid * 100;
        float acc = pb3[tid];
        for (int k = 0; k < 100; ++k) acc = fmaf(s_m2[k], w[k], acc);
        s_pr[tid] = acc;
        out[b * 100 + 40 + tid] = 1000.f * (acc - x[b * 160 + tid]);
    } else if (tid >= 128 && tid < 168) {
        int i = tid - 128;
        const float* w = vw3 + i * 100;
        float acc = vb3[i];
        for (int k = 0; k < 100; ++k) acc = fmaf(s_m2[128 + k], w[k], acc);
        s_vv[i] = acc;
        out[b * 100 + 60 + i] = 1000.f * (acc - x[b * 160 + 120 + i]);
    }
    __syncthreads();

    // =========================== LP phase ==================================
    if (tid >= 160) return;
    const int t = tid >> 5;
    const int l = tid & 31;
    const float* xt = xtraj + b * 45;
    const float* xb = x + b * 160;

    float* val = Lb + t * 32;
    float* Ag  = Lb + 160 + t * 408;
    float* bg  = Lb + 2200 + t * 17;

    // ---- value table ----
    {
        float v_ = 0.f;
        if (l == 1) v_ = 1.f;
        else if (l == 2) v_ = -1.f;
        else if (l >= 3 && l <= 10) {
            float r0 = xt[t], r1 = xt[5 + t];
            switch (l) {
                case 3:  v_ = r1 - s_pr[10 + t]; break;
                case 4:  v_ = r1 - s_pr[15 + t]; break;
                case 5:  v_ = s_pr[0 + t] - r0;  break;
                case 6:  v_ = s_pr[5 + t] - r0;  break;
                case 7:  v_ = r1 - xb[60 + 10 + t]; break;
                case 8:  v_ = r1 - xb[60 + 15 + t]; break;
                case 9:  v_ = xb[60 + 0 + t] - r0;  break;
                default: v_ = xb[60 + 5 + t] - r0;  break;
            }
        }
        else if (l >= 11 && l <= 16) v_ = -s_vv[5 * (l - 11) + t];
        else if (l >= 17 && l <= 22) v_ = xb[20 + 5 * (l - 17) + t];
        else if (l >= 23 && l <= 30) v_ = xb[80 + 5 * (l - 23) + t];
        val[l] = v_;
    }
    // ---- build dense A, b (intra-wave, DS in-order) ----
    for (int i = l; i < 408; i += 32) Ag[i] = 0.f;
    if (l < 17) {
        #pragma unroll
        for (int k = 0; k < 8; ++k) {
            int sel = AZ_SEL[l][k];
            if (sel != 0) Ag[l * 24 + (int)AZ_IDX[l][k]] = val[sel];
        }
        float bb = 0.f;
        if (l == 0) bb = xt[30 + t];
        else if (l == 1) bb = xt[35 + t];
        else if (l == 2) bb = xt[40 + t];
        else if (l == 5 || l == 8) bb = 1.f;
        bg[l] = bb;
    }

    // ---- numeric 12-slot window coefficients + c = (A^T b)_l ----
    const int bA = WBA[l], bB = WBB[l], bC = WBC[l];
    float cf[12];
    float cc = 0.f;
    #pragma unroll
    for (int k = 0; k < 12; ++k) cf[k] = 0.f;
    if (l < 24) {
        int e0 = AT_IDX[l][0], e1 = AT_IDX[l][1], e2 = AT_IDX[l][2];
        float a0 = Ag[e0 * 24 + l], a1 = Ag[e1 * 24 + l], a2 = Ag[e2 * 24 + l];
        cc = a0 * bg[e0] + a1 * bg[e1] + a2 * bg[e2];
        #pragma unroll
        for (int s = 0; s < 4; ++s)
            cf[s] = a0 * Ag[e0 * 24 + bA + s] + a1 * Ag[e1 * 24 + bA + s] + a2 * Ag[e2 * 24 + bA + s];
        #pragma unroll
        for (int s = 0; s < 4; ++s)
            cf[4 + s] = a0 * Ag[e0 * 24 + bB + s] + a1 * Ag[e1 * 24 + bB + s] + a2 * Ag[e2 * 24 + bB + s];
        if (l >= 4 && l < 12) {   // only rows 4..11 have a real C window
            #pragma unroll
            for (int s = 0; s < 4; ++s)
                cf[8 + s] = a0 * Ag[e0 * 24 + bC + s] + a1 * Ag[e1 * 24 + bC + s] + a2 * Ag[e2 * 24 + bC + s];
        }
    }

    const bool isF  = (l >= 4 && l < 8);
    const bool isNN = (l >= 12);

    // Mailbox: 32 floats per problem, overlaid on the (now dead) val region.
    float* Zg = Lb + t * 32;

    // dot of the 12 window slots against cf
    #define WDOT(vA, vB, vC)                                                    \
        (((cf[0]*vA.x + cf[1]*vA.y) + (cf[2]*vA.z + cf[3]*vA.w)) +              \
         ((cf[4]*vB.x + cf[5]*vB.y) + (cf[6]*vB.z + cf[7]*vB.w)) +              \
         ((cf[8]*vC.x + cf[9]*vC.y) + (cf[10]*vC.z + cf[11]*vC.w)))

    // ---- spectral norm: 25 M-applications, normalize every 5 ----
    float u = (l < 24) ? 1.f : 0.f;
    #pragma unroll 1
    for (int o = 0; o < 5; ++o) {
        #pragma unroll 1
        for (int ii = 0; ii < 5; ++ii) {
            Zg[l] = u;
            float4 vA = *(const float4*)(Zg + bA);
            float4 vB = *(const float4*)(Zg + bB);
            float4 vC = *(const float4*)(Zg + bC);
            u = WDOT(vA, vB, vC);
        }
        float s = u * u;
        s += __shfl_xor(s, 16, 32); s += __shfl_xor(s, 8, 32);
        s += __shfl_xor(s, 4, 32);  s += __shfl_xor(s, 2, 32);
        s += __shfl_xor(s, 1, 32);
        u = u / (sqrtf(s) + 1e-12f);
    }
    float tau;
    {
        Zg[l] = u;
        float4 vA = *(const float4*)(Zg + bA);
        float4 vB = *(const float4*)(Zg + bB);
        float4 vC = *(const float4*)(Zg + bC);
        float w = WDOT(vA, vB, vC);
        float s2 = u * w;   // u^T M u = ||A u||^2
        s2 += __shfl_xor(s2, 16, 32); s2 += __shfl_xor(s2, 8, 32);
        s2 += __shfl_xor(s2, 4, 32);  s2 += __shfl_xor(s2, 2, 32);
        s2 += __shfl_xor(s2, 1, 32);
        tau = 0.9f / (sqrtf(fmaxf(s2, 0.f)) + 1e-8f);
    }

    // ---- prescale by tau^2: Q += (t2*M)zb - t2*c;  g = z - Q ----
    const float t2 = tau * tau;
    #pragma unroll
    for (int k = 0; k < 12; ++k) cf[k] *= t2;
    const float cc2 = cc * t2;

    float zv = 0.f, zbv = 0.f, Q = 0.f;
    #pragma unroll 1
    for (int it = 0; it < 400; ++it) {
        Zg[l] = zbv;                                  // ds_write_b32
        float4 vA = *(const float4*)(Zg + bA);        // 3x ds_read_b128
        float4 vB = *(const float4*)(Zg + bB);
        float4 vC = *(const float4*)(Zg + bC);
        float Qm = Q - cc2;                           // overlaps read wait
        float s = WDOT(vA, vB, vC);
        Q = Qm + s;

        float gg = zv - Q;
        float cl = fminf(fmaxf(gg, -tau), tau);       // med3 clamp
        float st = gg - cl;                           // soft-threshold
        float nn = fmaxf(gg, 0.f);
        float zn = isF ? st : (isNN ? nn : gg);
        zbv = fmaf(2.f, zn, -zv);
        zv = zn;
    }
    #undef WDOT

    // ---- write p (z0..z3) and f (z4..z7) ----
    {
        float* ob = out + b * 100;
        if (l < 4)      ob[l * 5 + t]            = 100.f * zv;
        else if (l < 8) ob[20 + (l - 4) * 5 + t] = 100.f * zv;
    }
}

extern "C" void kernel_launch(void* const* d_in, const int* in_sizes, int n_in,
                              void* d_out, int out_size, void* d_ws, size_t ws_size,
                              hipStream_t stream) {
    const float* xtraj = (const float*)d_in[0];
    const float* x     = (const float*)d_in[1];
    const float* x_img = (const float*)d_in[2];
    const float* cw1 = (const float*)d_in[3];
    const float* cb1 = (const float*)d_in[4];
    const float* cw2 = (const float*)d_in[5];
    const float* cb2 = (const float*)d_in[6];
    const float* w3  = (const float*)d_in[7];
    const float* b3  = (const float*)d_in[8];
    const float* w4  = (const float*)d_in[9];
    const float* b4  = (const float*)d_in[10];
    const float* pw1 = (const float*)d_in[11];
    const float* pb1 = (const float*)d_in[12];
    const float* pw2 = (const float*)d_in[13];
    const float* pb2 = (const float*)d_in[14];
    const float* pw3 = (const float*)d_in[15];
    const float* pb3 = (const float*)d_in[16];
    const float* vw1 = (const float*)d_in[17];
    const float* vb1 = (const float*)d_in[18];
    const float* vw2 = (const float*)d_in[19];
    const float* vb2 = (const float*)d_in[20];
    const float* vw3 = (const float*)d_in[21];
    const float* vb3 = (const float*)d_in[22];

    float* out = (float*)d_out;
    const int Bn = in_sizes[0] / 45;

    float* ws_h1 = (float*)d_ws;   // Bn*4000 floats (~8.2 MB)

    conv1_kernel<<<Bn * 4, 128, 0, stream>>>(x_img, cw1, cb1, ws_h1);

    head_lp_kernel<<<Bn, 320, 0, stream>>>(
        xtraj, x, ws_h1, cw2, cb2, w3, b3, w4, b4,
        pw1, pb1, pw2, pb2, pw3, pb3, vw1, vb1, vw2, vb2, vw3, vb3,
        out);
}

// Round 9
// 235.366 us; speedup vs baseline: 1.1563x; 1.0312x over previous
//
#include <hip/hip_runtime.h>

// ---------------------------------------------------------------------------
// LP structure tables (verified rounds 3-8).
// ---------------------------------------------------------------------------
__device__ const signed char AZ_IDX[32][8] = {
    {4,5,6,7,8,9,0,0},{10,11,0,0,0,0,0,0},{4,5,6,7,8,9,10,11},
    {0,12,14,0,0,0,0,0},{2,12,14,0,0,0,0,0},{12,14,0,0,0,0,0,0},
    {1,13,15,0,0,0,0,0},{3,13,15,0,0,0,0,0},{13,15,0,0,0,0,0,0},
    {16,18,4,0,0,0,0,0},{16,18,6,0,0,0,0,0},{17,19,5,0,0,0,0,0},
    {17,19,7,0,0,0,0,0},{20,21,8,0,0,0,0,0},{20,21,10,0,0,0,0,0},
    {22,23,9,0,0,0,0,0},{22,23,11,0,0,0,0,0},
    {0},{0},{0},{0},{0},{0},{0},{0},{0},{0},{0},{0},{0},{0},{0}
};
__device__ const signed char AZ_SEL[32][8] = {
    {1,1,1,1,1,1,0,0},{1,1,0,0,0,0,0,0},{3,4,5,6,7,8,9,10},
    {1,11,13,0,0,0,0,0},{1,12,14,0,0,0,0,0},{1,1,0,0,0,0,0,0},
    {1,13,15,0,0,0,0,0},{1,14,16,0,0,0,0,0},{1,1,0,0,0,0,0,0},
    {17,19,2,0,0,0,0,0},{18,20,2,0,0,0,0,0},{19,21,2,0,0,0,0,0},
    {20,22,2,0,0,0,0,0},{23,25,2,0,0,0,0,0},{24,26,2,0,0,0,0,0},
    {27,29,2,0,0,0,0,0},{28,30,2,0,0,0,0,0},
    {0},{0},{0},{0},{0},{0},{0},{0},{0},{0},{0},{0},{0},{0},{0}
};
__device__ const signed char AT_IDX[32][3] = {
    {3,0,0},{6,0,0},{4,0,0},{7,0,0},
    {0,2,9},{0,2,11},{0,2,10},{0,2,12},{0,2,13},{0,2,15},{1,2,14},{1,2,16},
    {3,4,5},{6,7,8},{3,4,5},{6,7,8},
    {9,10,0},{11,12,0},{9,10,0},{11,12,0},
    {13,14,0},{13,14,0},{15,16,0},{15,16,0},
    {0},{0},{0},{0},{0},{0},{0},{0}
};
// Window bases for the 3 float4 mailbox reads (cover all M-row supports).
__device__ const signed char WBA[32] = {0,0,0,0, 4,4,4,4, 4,4,4,4, 0,0,0,0, 4,4,4,4, 8,8,8,8, 0,0,0,0,0,0,0,0};
__device__ const signed char WBB[32] = {12,12,12,12, 8,8,8,8, 8,8,8,8, 12,12,12,12, 16,16,16,16, 20,20,20,20, 0,0,0,0,0,0,0,0};
__device__ const signed char WBC[32] = {0,0,0,0, 16,16,16,16, 20,20,20,20, 0,0,0,0, 0,0,0,0, 0,0,0,0, 0,0,0,0,0,0,0,0};

// ---------------------------------------------------------------------------
// Single fused kernel: conv1 + conv2 + dense + MLPs + 5 LP solves per sample.
// 448 threads (7 waves): conv1's 400 pooled quads map one-per-thread.
// Image + cw1 stage into an overlay on the s_w2 region (dead until conv2),
// which is reloaded with cw2 after conv1.
// ---------------------------------------------------------------------------
__global__ __launch_bounds__(448) void net_kernel(
    const float* __restrict__ xtraj, const float* __restrict__ x,
    const float* __restrict__ x_img,
    const float* __restrict__ cw1, const float* __restrict__ cb1,
    const float* __restrict__ cw2, const float* __restrict__ cb2,
    const float* __restrict__ w3, const float* __restrict__ b3,
    const float* __restrict__ w4, const float* __restrict__ b4,
    const float* __restrict__ pw1, const float* __restrict__ pb1,
    const float* __restrict__ pw2, const float* __restrict__ pb2,
    const float* __restrict__ pw3, const float* __restrict__ pb3,
    const float* __restrict__ vw1, const float* __restrict__ vb1,
    const float* __restrict__ vw2, const float* __restrict__ vb2,
    const float* __restrict__ vw3, const float* __restrict__ vb3,
    float* __restrict__ out)
{
    const int b = blockIdx.x;
    const int tid = threadIdx.x;

    __shared__ __align__(16) float s_h1[4000];   // conv1 out; later LP scratch
    __shared__ __align__(16) float s_w2[5000];   // overlay: img[0:2500]+cw1[2500:3710]; then cw2
    __shared__ __align__(16) float s_h2[320];
    __shared__ float s_cb1[10];
    __shared__ float s_hc[145];
    __shared__ float s_t1[152];
    __shared__ float s_m1[256];
    __shared__ float s_m2[256];

    float* Lb = s_h1;
    float* s_pr = Lb + 2285;
    float* s_vv = Lb + 2305;

    float* s_img = s_w2;          // 2500
    float* s_cw1 = s_w2 + 2500;   // 1210

    // ---- phase 0: stage image (float4) + conv1 weights ----
    {
        const float4* src = (const float4*)(x_img + (size_t)b * 2500);
        float4* dst = (float4*)s_img;
        for (int i = tid; i < 625; i += 448) dst[i] = src[i];
        for (int i = tid; i < 1210; i += 448) s_cw1[i] = cw1[i];
        if (tid < 10) s_cb1[tid] = cb1[tid];
    }
    __syncthreads();

    // ---- phase 1: conv1 (11x11, 50->40) + maxpool2 + relu, 1 quad/thread ----
    if (tid < 400) {
        const int py = tid / 20, px = tid % 20;
        const int C = 2 * px;
        float acc0[10], acc1[10], acc2[10], acc3[10];
        #pragma unroll
        for (int oc = 0; oc < 10; ++oc) { acc0[oc] = 0.f; acc1[oc] = 0.f; acc2[oc] = 0.f; acc3[oc] = 0.f; }
        for (int r = 0; r < 12; ++r) {
            float v[12];
            #pragma unroll
            for (int j = 0; j < 6; ++j) {
                float2 t = *(const float2*)&s_img[(2 * py + r) * 50 + C + 2 * j];
                v[2 * j] = t.x; v[2 * j + 1] = t.y;
            }
            if (r < 11) {
                #pragma unroll
                for (int oc = 0; oc < 10; ++oc) {
                    #pragma unroll
                    for (int kx = 0; kx < 11; ++kx) {
                        float w0 = s_cw1[oc * 121 + r * 11 + kx];   // broadcast
                        acc0[oc] = fmaf(v[kx], w0, acc0[oc]);
                        acc1[oc] = fmaf(v[kx + 1], w0, acc1[oc]);
                    }
                }
            }
            if (r >= 1) {
                #pragma unroll
                for (int oc = 0; oc < 10; ++oc) {
                    #pragma unroll
                    for (int kx = 0; kx < 11; ++kx) {
                        float w1 = s_cw1[oc * 121 + (r - 1) * 11 + kx];
                        acc2[oc] = fmaf(v[kx], w1, acc2[oc]);
                        acc3[oc] = fmaf(v[kx + 1], w1, acc3[oc]);
                    }
                }
            }
        }
        #pragma unroll
        for (int oc = 0; oc < 10; ++oc) {
            float m = fmaxf(fmaxf(acc0[oc], acc1[oc]), fmaxf(acc2[oc], acc3[oc]));
            s_h1[oc * 400 + tid] = fmaxf(m + s_cb1[oc], 0.f);
        }
    }
    __syncthreads();

    // ---- phase 2: reload s_w2 with conv2 weights ----
    {
        const float4* wsrc = (const float4*)cw2;
        float4* wdst = (float4*)s_w2;
        for (int i = tid; i < 1250; i += 448) wdst[i] = wsrc[i];
    }
    __syncthreads();

    // ---- conv2 (5x5, 20->16, 10ic->20oc) + maxpool4 + relu ----
    if (tid < 320) {
        const int oc = tid >> 4, cell = tid & 15;
        const int R0 = (cell >> 2) * 4, C0 = (cell & 3) * 4;
        float acc[16];
        #pragma unroll
        for (int i = 0; i < 16; ++i) acc[i] = 0.f;
        for (int ic = 0; ic < 10; ++ic) {
            const float* hb = &s_h1[ic * 400];
            const float* wb = &s_w2[oc * 250 + ic * 25];
            float v[8][8];
            #pragma unroll
            for (int r = 0; r < 8; ++r) {
                float4 t0 = *(const float4*)&hb[(R0 + r) * 20 + C0];
                float4 t1 = *(const float4*)&hb[(R0 + r) * 20 + C0 + 4];
                v[r][0] = t0.x; v[r][1] = t0.y; v[r][2] = t0.z; v[r][3] = t0.w;
                v[r][4] = t1.x; v[r][5] = t1.y; v[r][6] = t1.z; v[r][7] = t1.w;
            }
            #pragma unroll
            for (int k = 0; k < 5; ++k) {
                #pragma unroll
                for (int kx = 0; kx < 5; ++kx) {
                    float wv = wb[k * 5 + kx];
                    #pragma unroll
                    for (int o = 0; o < 4; ++o) {
                        #pragma unroll
                        for (int cc = 0; cc < 4; ++cc)
                            acc[o * 4 + cc] = fmaf(v[o + k][cc + kx], wv, acc[o * 4 + cc]);
                    }
                }
            }
        }
        float m = acc[0];
        #pragma unroll
        for (int i = 1; i < 16; ++i) m = fmaxf(m, acc[i]);
        s_h2[tid] = fmaxf(m + cb2[oc], 0.f);
    }
    __syncthreads();

    // ---- dense 320 -> 150, relu ----
    if (tid < 150) {
        const float* w = w3 + tid * 320;
        float a0 = b3[tid], a1 = 0.f, a2 = 0.f, a3 = 0.f;
        for (int k = 0; k < 320; k += 4) {
            a0 = fmaf(s_h2[k],     w[k],     a0);
            a1 = fmaf(s_h2[k + 1], w[k + 1], a1);
            a2 = fmaf(s_h2[k + 2], w[k + 2], a2);
            a3 = fmaf(s_h2[k + 3], w[k + 3], a3);
        }
        s_t1[tid] = fmaxf((a0 + a1) + (a2 + a3), 0.f);
    }
    __syncthreads();

    // ---- dense 150 -> 100, relu -> s_hc[0:100]; concat xtraj ----
    if (tid < 100) {
        const float* w = w4 + tid * 150;
        float a0 = b4[tid], a1 = 0.f;
        for (int k = 0; k < 150; k += 2) {
            a0 = fmaf(s_t1[k],     w[k],     a0);
            a1 = fmaf(s_t1[k + 1], w[k + 1], a1);
        }
        s_hc[tid] = fmaxf(a0 + a1, 0.f);
    }
    if (tid >= 100 && tid < 145) s_hc[tid] = xtraj[b * 45 + (tid - 100)];
    __syncthreads();

    // ---- two MLPs in parallel ----
    if (tid < 100) {
        const float* w = pw1 + tid * 145;
        float acc = pb1[tid];
        for (int k = 0; k < 145; ++k) acc = fmaf(s_hc[k], w[k], acc);
        s_m1[tid] = fmaxf(acc, 0.f);
    } else if (tid >= 128 && tid < 228) {
        int i = tid - 128;
        const float* w = vw1 + i * 145;
        float acc = vb1[i];
        for (int k = 0; k < 145; ++k) acc = fmaf(s_hc[k], w[k], acc);
        s_m1[tid] = fmaxf(acc, 0.f);
    }
    __syncthreads();

    if (tid < 100) {
        const float* w = pw2 + tid * 100;
        float acc = pb2[tid];
        for (int k = 0; k < 100; ++k) acc = fmaf(s_m1[k], w[k], acc);
        s_m2[tid] = fmaxf(acc, 0.f);
    } else if (tid >= 128 && tid < 228) {
        int i = tid - 128;
        const float* w = vw2 + i * 100;
        float acc = vb2[i];
        for (int k = 0; k < 100; ++k) acc = fmaf(s_m1[128 + k], w[k], acc);
        s_m2[tid] = fmaxf(acc, 0.f);
    }
    __syncthreads();

    if (tid < 20) {
        const float* w = pw3 + tid * 100;
        float acc = pb3[tid];
        for (int k = 0; k < 100; ++k) acc = fmaf(s_m2[k], w[k], acc);
        s_pr[tid] = acc;
        out[b * 100 + 40 + tid] = 1000.f * (acc - x[b * 160 + tid]);
    } else if (tid >= 128 && tid < 168) {
        int i = tid - 128;
        const float* w = vw3 + i * 100;
        float acc = vb3[i];
        for (int k = 0; k < 100; ++k) acc = fmaf(s_m2[128 + k], w[k], acc);
        s_vv[i] = acc;
        out[b * 100 + 60 + i] = 1000.f * (acc - x[b * 160 + 120 + i]);
    }
    __syncthreads();

    // =========================== LP phase ==================================
    if (tid >= 160) return;
    const int t = tid >> 5;
    const int l = tid & 31;
    const float* xt = xtraj + b * 45;
    const float* xb = x + b * 160;

    float* val = Lb + t * 32;
    float* Ag  = Lb + 160 + t * 408;
    float* bg  = Lb + 2200 + t * 17;

    // ---- value table ----
    {
        float v_ = 0.f;
        if (l == 1) v_ = 1.f;
        else if (l == 2) v_ = -1.f;
        else if (l >= 3 && l <= 10) {
            float r0 = xt[t], r1 = xt[5 + t];
            switch (l) {
                case 3:  v_ = r1 - s_pr[10 + t]; break;
                case 4:  v_ = r1 - s_pr[15 + t]; break;
                case 5:  v_ = s_pr[0 + t] - r0;  break;
                case 6:  v_ = s_pr[5 + t] - r0;  break;
                case 7:  v_ = r1 - xb[60 + 10 + t]; break;
                case 8:  v_ = r1 - xb[60 + 15 + t]; break;
                case 9:  v_ = xb[60 + 0 + t] - r0;  break;
                default: v_ = xb[60 + 5 + t] - r0;  break;
            }
        }
        else if (l >= 11 && l <= 16) v_ = -s_vv[5 * (l - 11) + t];
        else if (l >= 17 && l <= 22) v_ = xb[20 + 5 * (l - 17) + t];
        else if (l >= 23 && l <= 30) v_ = xb[80 + 5 * (l - 23) + t];
        val[l] = v_;
    }
    // ---- build dense A, b (intra-wave, DS in-order) ----
    for (int i = l; i < 408; i += 32) Ag[i] = 0.f;
    if (l < 17) {
        #pragma unroll
        for (int k = 0; k < 8; ++k) {
            int sel = AZ_SEL[l][k];
            if (sel != 0) Ag[l * 24 + (int)AZ_IDX[l][k]] = val[sel];
        }
        float bb = 0.f;
        if (l == 0) bb = xt[30 + t];
        else if (l == 1) bb = xt[35 + t];
        else if (l == 2) bb = xt[40 + t];
        else if (l == 5 || l == 8) bb = 1.f;
        bg[l] = bb;
    }

    // ---- numeric 12-slot window coefficients + c = (A^T b)_l ----
    const int bA = WBA[l], bB = WBB[l], bC = WBC[l];
    float cf[12];
    float cc = 0.f;
    #pragma unroll
    for (int k = 0; k < 12; ++k) cf[k] = 0.f;
    if (l < 24) {
        int e0 = AT_IDX[l][0], e1 = AT_IDX[l][1], e2 = AT_IDX[l][2];
        float a0 = Ag[e0 * 24 + l], a1 = Ag[e1 * 24 + l], a2 = Ag[e2 * 24 + l];
        cc = a0 * bg[e0] + a1 * bg[e1] + a2 * bg[e2];
        #pragma unroll
        for (int s = 0; s < 4; ++s)
            cf[s] = a0 * Ag[e0 * 24 + bA + s] + a1 * Ag[e1 * 24 + bA + s] + a2 * Ag[e2 * 24 + bA + s];
        #pragma unroll
        for (int s = 0; s < 4; ++s)
            cf[4 + s] = a0 * Ag[e0 * 24 + bB + s] + a1 * Ag[e1 * 24 + bB + s] + a2 * Ag[e2 * 24 + bB + s];
        if (l >= 4 && l < 12) {
            #pragma unroll
            for (int s = 0; s < 4; ++s)
                cf[8 + s] = a0 * Ag[e0 * 24 + bC + s] + a1 * Ag[e1 * 24 + bC + s] + a2 * Ag[e2 * 24 + bC + s];
        }
    }

    const bool isF  = (l >= 4 && l < 8);
    const bool isNN = (l >= 12);

    float* Zg = Lb + t * 32;   // mailbox (overlays dead val region)

    #define WDOT(vA, vB, vC)                                                    \
        (((cf[0]*vA.x + cf[1]*vA.y) + (cf[2]*vA.z + cf[3]*vA.w)) +              \
         ((cf[4]*vB.x + cf[5]*vB.y) + (cf[6]*vB.z + cf[7]*vB.w)) +              \
         ((cf[8]*vC.x + cf[9]*vC.y) + (cf[10]*vC.z + cf[11]*vC.w)))

    // ---- spectral norm: 25 M-applications, normalize every 5 ----
    float u = (l < 24) ? 1.f : 0.f;
    #pragma unroll 1
    for (int o = 0; o < 5; ++o) {
        #pragma unroll 1
        for (int ii = 0; ii < 5; ++ii) {
            Zg[l] = u;
            float4 vA = *(const float4*)(Zg + bA);
            float4 vB = *(const float4*)(Zg + bB);
            float4 vC = *(const float4*)(Zg + bC);
            u = WDOT(vA, vB, vC);
        }
        float s = u * u;
        s += __shfl_xor(s, 16, 32); s += __shfl_xor(s, 8, 32);
        s += __shfl_xor(s, 4, 32);  s += __shfl_xor(s, 2, 32);
        s += __shfl_xor(s, 1, 32);
        u = u / (sqrtf(s) + 1e-12f);
    }
    float tau;
    {
        Zg[l] = u;
        float4 vA = *(const float4*)(Zg + bA);
        float4 vB = *(const float4*)(Zg + bB);
        float4 vC = *(const float4*)(Zg + bC);
        float w = WDOT(vA, vB, vC);
        float s2 = u * w;   // u^T M u = ||A u||^2
        s2 += __shfl_xor(s2, 16, 32); s2 += __shfl_xor(s2, 8, 32);
        s2 += __shfl_xor(s2, 4, 32);  s2 += __shfl_xor(s2, 2, 32);
        s2 += __shfl_xor(s2, 1, 32);
        tau = 0.9f / (sqrtf(fmaxf(s2, 0.f)) + 1e-8f);
    }

    // ---- prescale by tau^2 ----
    const float t2 = tau * tau;
    #pragma unroll
    for (int k = 0; k < 12; ++k) cf[k] *= t2;
    const float cc2 = cc * t2;

    float zv = 0.f, zbv = 0.f, Q = 0.f;
    #pragma unroll 1
    for (int it = 0; it < 400; ++it) {
        Zg[l] = zbv;                                  // ds_write_b32
        float4 vA = *(const float4*)(Zg + bA);        // 3x ds_read_b128
        float4 vB = *(const float4*)(Zg + bB);
        float4 vC = *(const float4*)(Zg + bC);
        float Qm = Q - cc2;                           // overlaps read wait
        float s = WDOT(vA, vB, vC);
        Q = Qm + s;

        float gg = zv - Q;
        float cl = fminf(fmaxf(gg, -tau), tau);       // med3 clamp
        float st = gg - cl;                           // soft-threshold
        float nn = fmaxf(gg, 0.f);
        float zn = isF ? st : (isNN ? nn : gg);
        zbv = fmaf(2.f, zn, -zv);
        zv = zn;
    }
    #undef WDOT

    // ---- write p (z0..z3) and f (z4..z7) ----
    {
        float* ob = out + b * 100;
        if (l < 4)      ob[l * 5 + t]            = 100.f * zv;
        else if (l < 8) ob[20 + (l - 4) * 5 + t] = 100.f * zv;
    }
}

extern "C" void kernel_launch(void* const* d_in, const int* in_sizes, int n_in,
                              void* d_out, int out_size, void* d_ws, size_t ws_size,
                              hipStream_t stream) {
    const float* xtraj = (const float*)d_in[0];
    const float* x     = (const float*)d_in[1];
    const float* x_img = (const float*)d_in[2];
    const float* cw1 = (const float*)d_in[3];
    const float* cb1 = (const float*)d_in[4];
    const float* cw2 = (const float*)d_in[5];
    const float* cb2 = (const float*)d_in[6];
    const float* w3  = (const float*)d_in[7];
    const float* b3  = (const float*)d_in[8];
    const float* w4  = (const float*)d_in[9];
    const float* b4  = (const float*)d_in[10];
    const float* pw1 = (const float*)d_in[11];
    const float* pb1 = (const float*)d_in[12];
    const float* pw2 = (const float*)d_in[13];
    const float* pb2 = (const float*)d_in[14];
    const float* pw3 = (const float*)d_in[15];
    const float* pb3 = (const float*)d_in[16];
    const float* vw1 = (const float*)d_in[17];
    const float* vb1 = (const float*)d_in[18];
    const float* vw2 = (const float*)d_in[19];
    const float* vb2 = (const float*)d_in[20];
    const float* vw3 = (const float*)d_in[21];
    const float* vb3 = (const float*)d_in[22];

    float* out = (float*)d_out;
    const int Bn = in_sizes[0] / 45;

    net_kernel<<<Bn, 448, 0, stream>>>(
        xtraj, x, x_img, cw1, cb1, cw2, cb2, w3, b3, w4, b4,
        pw1, pb1, pw2, pb2, pw3, pb3, vw1, vb1, vw2, vb2, vw3, vb3,
        out);
}

// Round 11
// 221.908 us; speedup vs baseline: 1.2264x; 1.0606x over previous
//
#include <hip/hip_runtime.h>

// ---------------------------------------------------------------------------
// LP structure tables (verified rounds 3-9).
// ---------------------------------------------------------------------------
__device__ const signed char AZ_IDX[32][8] = {
    {4,5,6,7,8,9,0,0},{10,11,0,0,0,0,0,0},{4,5,6,7,8,9,10,11},
    {0,12,14,0,0,0,0,0},{2,12,14,0,0,0,0,0},{12,14,0,0,0,0,0,0},
    {1,13,15,0,0,0,0,0},{3,13,15,0,0,0,0,0},{13,15,0,0,0,0,0,0},
    {16,18,4,0,0,0,0,0},{16,18,6,0,0,0,0,0},{17,19,5,0,0,0,0,0},
    {17,19,7,0,0,0,0,0},{20,21,8,0,0,0,0,0},{20,21,10,0,0,0,0,0},
    {22,23,9,0,0,0,0,0},{22,23,11,0,0,0,0,0},
    {0},{0},{0},{0},{0},{0},{0},{0},{0},{0},{0},{0},{0},{0},{0}
};
__device__ const signed char AZ_SEL[32][8] = {
    {1,1,1,1,1,1,0,0},{1,1,0,0,0,0,0,0},{3,4,5,6,7,8,9,10},
    {1,11,13,0,0,0,0,0},{1,12,14,0,0,0,0,0},{1,1,0,0,0,0,0,0},
    {1,13,15,0,0,0,0,0},{1,14,16,0,0,0,0,0},{1,1,0,0,0,0,0,0},
    {17,19,2,0,0,0,0,0},{18,20,2,0,0,0,0,0},{19,21,2,0,0,0,0,0},
    {20,22,2,0,0,0,0,0},{23,25,2,0,0,0,0,0},{24,26,2,0,0,0,0,0},
    {27,29,2,0,0,0,0,0},{28,30,2,0,0,0,0,0},
    {0},{0},{0},{0},{0},{0},{0},{0},{0},{0},{0},{0},{0},{0},{0}
};
__device__ const signed char AT_IDX[32][3] = {
    {3,0,0},{6,0,0},{4,0,0},{7,0,0},
    {0,2,9},{0,2,11},{0,2,10},{0,2,12},{0,2,13},{0,2,15},{1,2,14},{1,2,16},
    {3,4,5},{6,7,8},{3,4,5},{6,7,8},
    {9,10,0},{11,12,0},{9,10,0},{11,12,0},
    {13,14,0},{13,14,0},{15,16,0},{15,16,0},
    {0},{0},{0},{0},{0},{0},{0},{0}
};
// Window bases for the 3 float4 mailbox reads (cover all M-row supports).
__device__ const signed char WBA[32] = {0,0,0,0, 4,4,4,4, 4,4,4,4, 0,0,0,0, 4,4,4,4, 8,8,8,8, 0,0,0,0,0,0,0,0};
__device__ const signed char WBB[32] = {12,12,12,12, 8,8,8,8, 8,8,8,8, 12,12,12,12, 16,16,16,16, 20,20,20,20, 0,0,0,0,0,0,0,0};
__device__ const signed char WBC[32] = {0,0,0,0, 16,16,16,16, 20,20,20,20, 0,0,0,0, 0,0,0,0, 0,0,0,0, 0,0,0,0,0,0,0,0};

#define LP_ITERS 400   // R10 FAILED at 300 (absmax 1616): 400 is a correctness constraint.

// ---------------------------------------------------------------------------
// Single fused kernel: conv1 + conv2 + dense + MLPs + 5 LP solves per sample.
// 448 threads (7 waves). conv1 weights read from GLOBAL (wave-uniform ->
// scalar s_load path, zero DS cost); only the image is staged in LDS.
// ---------------------------------------------------------------------------
__global__ __launch_bounds__(448) void net_kernel(
    const float* __restrict__ xtraj, const float* __restrict__ x,
    const float* __restrict__ x_img,
    const float* __restrict__ cw1, const float* __restrict__ cb1,
    const float* __restrict__ cw2, const float* __restrict__ cb2,
    const float* __restrict__ w3, const float* __restrict__ b3,
    const float* __restrict__ w4, const float* __restrict__ b4,
    const float* __restrict__ pw1, const float* __restrict__ pb1,
    const float* __restrict__ pw2, const float* __restrict__ pb2,
    const float* __restrict__ pw3, const float* __restrict__ pb3,
    const float* __restrict__ vw1, const float* __restrict__ vb1,
    const float* __restrict__ vw2, const float* __restrict__ vb2,
    const float* __restrict__ vw3, const float* __restrict__ vb3,
    float* __restrict__ out)
{
    const int b = blockIdx.x;
    const int tid = threadIdx.x;

    __shared__ __align__(16) float s_h1[4000];   // conv1 out; later LP scratch
    __shared__ __align__(16) float s_w2[5000];   // overlay: img[0:2500]; then cw2
    __shared__ __align__(16) float s_h2[320];
    __shared__ float s_hc[145];
    __shared__ float s_t1[152];
    __shared__ float s_m1[256];
    __shared__ float s_m2[256];

    float* Lb = s_h1;
    float* s_pr = Lb + 2285;
    float* s_vv = Lb + 2305;

    float* s_img = s_w2;          // 2500 (dead before conv2-weight reload)

    // ---- phase 0: stage image (float4) ----
    {
        const float4* src = (const float4*)(x_img + (size_t)b * 2500);
        float4* dst = (float4*)s_img;
        for (int i = tid; i < 625; i += 448) dst[i] = src[i];
    }
    __syncthreads();

    // ---- phase 1: conv1 (11x11, 50->40) + maxpool2 + relu, 1 quad/thread ----
    // Weights from global: wave-uniform addresses -> scalar loads.
    if (tid < 400) {
        const int py = tid / 20, px = tid % 20;
        const int C = 2 * px;
        float acc0[10], acc1[10], acc2[10], acc3[10];
        #pragma unroll
        for (int oc = 0; oc < 10; ++oc) { acc0[oc] = 0.f; acc1[oc] = 0.f; acc2[oc] = 0.f; acc3[oc] = 0.f; }
        for (int r = 0; r < 12; ++r) {
            float v[12];
            #pragma unroll
            for (int j = 0; j < 6; ++j) {
                float2 t = *(const float2*)&s_img[(2 * py + r) * 50 + C + 2 * j];
                v[2 * j] = t.x; v[2 * j + 1] = t.y;
            }
            if (r < 11) {
                #pragma unroll
                for (int oc = 0; oc < 10; ++oc) {
                    #pragma unroll
                    for (int kx = 0; kx < 11; ++kx) {
                        float w0 = cw1[oc * 121 + r * 11 + kx];
                        acc0[oc] = fmaf(v[kx], w0, acc0[oc]);
                        acc1[oc] = fmaf(v[kx + 1], w0, acc1[oc]);
                    }
                }
            }
            if (r >= 1) {
                #pragma unroll
                for (int oc = 0; oc < 10; ++oc) {
                    #pragma unroll
                    for (int kx = 0; kx < 11; ++kx) {
                        float w1 = cw1[oc * 121 + (r - 1) * 11 + kx];
                        acc2[oc] = fmaf(v[kx], w1, acc2[oc]);
                        acc3[oc] = fmaf(v[kx + 1], w1, acc3[oc]);
                    }
                }
            }
        }
        #pragma unroll
        for (int oc = 0; oc < 10; ++oc) {
            float m = fmaxf(fmaxf(acc0[oc], acc1[oc]), fmaxf(acc2[oc], acc3[oc]));
            s_h1[oc * 400 + tid] = fmaxf(m + cb1[oc], 0.f);
        }
    }
    __syncthreads();

    // ---- phase 2: reload s_w2 with conv2 weights ----
    {
        const float4* wsrc = (const float4*)cw2;
        float4* wdst = (float4*)s_w2;
        for (int i = tid; i < 1250; i += 448) wdst[i] = wsrc[i];
    }
    __syncthreads();

    // ---- conv2 (5x5, 20->16, 10ic->20oc) + maxpool4 + relu ----
    if (tid < 320) {
        const int oc = tid >> 4, cell = tid & 15;
        const int R0 = (cell >> 2) * 4, C0 = (cell & 3) * 4;
        float acc[16];
        #pragma unroll
        for (int i = 0; i < 16; ++i) acc[i] = 0.f;
        for (int ic = 0; ic < 10; ++ic) {
            const float* hb = &s_h1[ic * 400];
            const float* wb = &s_w2[oc * 250 + ic * 25];
            float v[8][8];
            #pragma unroll
            for (int r = 0; r < 8; ++r) {
                float4 t0 = *(const float4*)&hb[(R0 + r) * 20 + C0];
                float4 t1 = *(const float4*)&hb[(R0 + r) * 20 + C0 + 4];
                v[r][0] = t0.x; v[r][1] = t0.y; v[r][2] = t0.z; v[r][3] = t0.w;
                v[r][4] = t1.x; v[r][5] = t1.y; v[r][6] = t1.z; v[r][7] = t1.w;
            }
            #pragma unroll
            for (int k = 0; k < 5; ++k) {
                #pragma unroll
                for (int kx = 0; kx < 5; ++kx) {
                    float wv = wb[k * 5 + kx];
                    #pragma unroll
                    for (int o = 0; o < 4; ++o) {
                        #pragma unroll
                        for (int cc = 0; cc < 4; ++cc)
                            acc[o * 4 + cc] = fmaf(v[o + k][cc + kx], wv, acc[o * 4 + cc]);
                    }
                }
            }
        }
        float m = acc[0];
        #pragma unroll
        for (int i = 1; i < 16; ++i) m = fmaxf(m, acc[i]);
        s_h2[tid] = fmaxf(m + cb2[oc], 0.f);
    }
    __syncthreads();

    // ---- dense 320 -> 150, relu ----
    if (tid < 150) {
        const float* w = w3 + tid * 320;
        float a0 = b3[tid], a1 = 0.f, a2 = 0.f, a3 = 0.f;
        for (int k = 0; k < 320; k += 4) {
            a0 = fmaf(s_h2[k],     w[k],     a0);
            a1 = fmaf(s_h2[k + 1], w[k + 1], a1);
            a2 = fmaf(s_h2[k + 2], w[k + 2], a2);
            a3 = fmaf(s_h2[k + 3], w[k + 3], a3);
        }
        s_t1[tid] = fmaxf((a0 + a1) + (a2 + a3), 0.f);
    }
    __syncthreads();

    // ---- dense 150 -> 100, relu -> s_hc[0:100]; concat xtraj ----
    if (tid < 100) {
        const float* w = w4 + tid * 150;
        float a0 = b4[tid], a1 = 0.f;
        for (int k = 0; k < 150; k += 2) {
            a0 = fmaf(s_t1[k],     w[k],     a0);
            a1 = fmaf(s_t1[k + 1], w[k + 1], a1);
        }
        s_hc[tid] = fmaxf(a0 + a1, 0.f);
    }
    if (tid >= 100 && tid < 145) s_hc[tid] = xtraj[b * 45 + (tid - 100)];
    __syncthreads();

    // ---- two MLPs in parallel ----
    if (tid < 100) {
        const float* w = pw1 + tid * 145;
        float acc = pb1[tid];
        for (int k = 0; k < 145; ++k) acc = fmaf(s_hc[k], w[k], acc);
        s_m1[tid] = fmaxf(acc, 0.f);
    } else if (tid >= 128 && tid < 228) {
        int i = tid - 128;
        const float* w = vw1 + i * 145;
        float acc = vb1[i];
        for (int k = 0; k < 145; ++k) acc = fmaf(s_hc[k], w[k], acc);
        s_m1[tid] = fmaxf(acc, 0.f);
    }
    __syncthreads();

    if (tid < 100) {
        const float* w = pw2 + tid * 100;
        float acc = pb2[tid];
        for (int k = 0; k < 100; ++k) acc = fmaf(s_m1[k], w[k], acc);
        s_m2[tid] = fmaxf(acc, 0.f);
    } else if (tid >= 128 && tid < 228) {
        int i = tid - 128;
        const float* w = vw2 + i * 100;
        float acc = vb2[i];
        for (int k = 0; k < 100; ++k) acc = fmaf(s_m1[128 + k], w[k], acc);
        s_m2[tid] = fmaxf(acc, 0.f);
    }
    __syncthreads();

    if (tid < 20) {
        const float* w = pw3 + tid * 100;
        float acc = pb3[tid];
        for (int k = 0; k < 100; ++k) acc = fmaf(s_m2[k], w[k], acc);
        s_pr[tid] = acc;
        out[b * 100 + 40 + tid] = 1000.f * (acc - x[b * 160 + tid]);
    } else if (tid >= 128 && tid < 168) {
        int i = tid - 128;
        const float* w = vw3 + i * 100;
        float acc = vb3[i];
        for (int k = 0; k < 100; ++k) acc = fmaf(s_m2[128 + k], w[k], acc);
        s_vv[i] = acc;
        out[b * 100 + 60 + i] = 1000.f * (acc - x[b * 160 + 120 + i]);
    }
    __syncthreads();

    // =========================== LP phase ==================================
    if (tid >= 160) return;
    const int t = tid >> 5;
    const int l = tid & 31;
    const float* xt = xtraj + b * 45;
    const float* xb = x + b * 160;

    float* val = Lb + t * 32;
    float* Ag  = Lb + 160 + t * 408;
    float* bg  = Lb + 2200 + t * 17;

    // ---- value table ----
    {
        float v_ = 0.f;
        if (l == 1) v_ = 1.f;
        else if (l == 2) v_ = -1.f;
        else if (l >= 3 && l <= 10) {
            float r0 = xt[t], r1 = xt[5 + t];
            switch (l) {
                case 3:  v_ = r1 - s_pr[10 + t]; break;
                case 4:  v_ = r1 - s_pr[15 + t]; break;
                case 5:  v_ = s_pr[0 + t] - r0;  break;
                case 6:  v_ = s_pr[5 + t] - r0;  break;
                case 7:  v_ = r1 - xb[60 + 10 + t]; break;
                case 8:  v_ = r1 - xb[60 + 15 + t]; break;
                case 9:  v_ = xb[60 + 0 + t] - r0;  break;
                default: v_ = xb[60 + 5 + t] - r0;  break;
            }
        }
        else if (l >= 11 && l <= 16) v_ = -s_vv[5 * (l - 11) + t];
        else if (l >= 17 && l <= 22) v_ = xb[20 + 5 * (l - 17) + t];
        else if (l >= 23 && l <= 30) v_ = xb[80 + 5 * (l - 23) + t];
        val[l] = v_;
    }
    // ---- build dense A, b (intra-wave, DS in-order) ----
    for (int i = l; i < 408; i += 32) Ag[i] = 0.f;
    if (l < 17) {
        #pragma unroll
        for (int k = 0; k < 8; ++k) {
            int sel = AZ_SEL[l][k];
            if (sel != 0) Ag[l * 24 + (int)AZ_IDX[l][k]] = val[sel];
        }
        float bb = 0.f;
        if (l == 0) bb = xt[30 + t];
        else if (l == 1) bb = xt[35 + t];
        else if (l == 2) bb = xt[40 + t];
        else if (l == 5 || l == 8) bb = 1.f;
        bg[l] = bb;
    }

    // ---- numeric 12-slot window coefficients + c = (A^T b)_l ----
    const int bA = WBA[l], bB = WBB[l], bC = WBC[l];
    float cf[12];
    float cc = 0.f;
    #pragma unroll
    for (int k = 0; k < 12; ++k) cf[k] = 0.f;
    if (l < 24) {
        int e0 = AT_IDX[l][0], e1 = AT_IDX[l][1], e2 = AT_IDX[l][2];
        float a0 = Ag[e0 * 24 + l], a1 = Ag[e1 * 24 + l], a2 = Ag[e2 * 24 + l];
        cc = a0 * bg[e0] + a1 * bg[e1] + a2 * bg[e2];
        #pragma unroll
        for (int s = 0; s < 4; ++s)
            cf[s] = a0 * Ag[e0 * 24 + bA + s] + a1 * Ag[e1 * 24 + bA + s] + a2 * Ag[e2 * 24 + bA + s];
        #pragma unroll
        for (int s = 0; s < 4; ++s)
            cf[4 + s] = a0 * Ag[e0 * 24 + bB + s] + a1 * Ag[e1 * 24 + bB + s] + a2 * Ag[e2 * 24 + bB + s];
        if (l >= 4 && l < 12) {
            #pragma unroll
            for (int s = 0; s < 4; ++s)
                cf[8 + s] = a0 * Ag[e0 * 24 + bC + s] + a1 * Ag[e1 * 24 + bC + s] + a2 * Ag[e2 * 24 + bC + s];
        }
    }

    const bool isF  = (l >= 4 && l < 8);
    const bool isNN = (l >= 12);

    float* Zg = Lb + t * 32;   // mailbox (overlays dead val region)

    #define WDOT(vA, vB, vC)                                                    \
        (((cf[0]*vA.x + cf[1]*vA.y) + (cf[2]*vA.z + cf[3]*vA.w)) +              \
         ((cf[4]*vB.x + cf[5]*vB.y) + (cf[6]*vB.z + cf[7]*vB.w)) +              \
         ((cf[8]*vC.x + cf[9]*vC.y) + (cf[10]*vC.z + cf[11]*vC.w)))

    // ---- spectral norm: 25 M-applications, normalize every 5 ----
    float u = (l < 24) ? 1.f : 0.f;
    #pragma unroll 1
    for (int o = 0; o < 5; ++o) {
        #pragma unroll 1
        for (int ii = 0; ii < 5; ++ii) {
            Zg[l] = u;
            float4 vA = *(const float4*)(Zg + bA);
            float4 vB = *(const float4*)(Zg + bB);
            float4 vC = *(const float4*)(Zg + bC);
            u = WDOT(vA, vB, vC);
        }
        float s = u * u;
        s += __shfl_xor(s, 16, 32); s += __shfl_xor(s, 8, 32);
        s += __shfl_xor(s, 4, 32);  s += __shfl_xor(s, 2, 32);
        s += __shfl_xor(s, 1, 32);
        u = u / (sqrtf(s) + 1e-12f);
    }
    float tau;
    {
        Zg[l] = u;
        float4 vA = *(const float4*)(Zg + bA);
        float4 vB = *(const float4*)(Zg + bB);
        float4 vC = *(const float4*)(Zg + bC);
        float w = WDOT(vA, vB, vC);
        float s2 = u * w;   // u^T M u = ||A u||^2
        s2 += __shfl_xor(s2, 16, 32); s2 += __shfl_xor(s2, 8, 32);
        s2 += __shfl_xor(s2, 4, 32);  s2 += __shfl_xor(s2, 2, 32);
        s2 += __shfl_xor(s2, 1, 32);
        tau = 0.9f / (sqrtf(fmaxf(s2, 0.f)) + 1e-8f);
    }

    // ---- prescale by tau^2 ----
    const float t2 = tau * tau;
    #pragma unroll
    for (int k = 0; k < 12; ++k) cf[k] *= t2;
    const float cc2 = cc * t2;

    float zv = 0.f, zbv = 0.f, Q = 0.f;
    #pragma unroll 1
    for (int it = 0; it < LP_ITERS; ++it) {
        Zg[l] = zbv;                                  // ds_write_b32
        float4 vA = *(const float4*)(Zg + bA);        // 3x ds_read_b128
        float4 vB = *(const float4*)(Zg + bB);
        float4 vC = *(const float4*)(Zg + bC);
        float Qm = Q - cc2;                           // overlaps read wait
        float s = WDOT(vA, vB, vC);
        Q = Qm + s;

        float gg = zv - Q;
        float cl = fminf(fmaxf(gg, -tau), tau);       // med3 clamp
        float st = gg - cl;                           // soft-threshold
        float nn = fmaxf(gg, 0.f);
        float zn = isF ? st : (isNN ? nn : gg);
        zbv = fmaf(2.f, zn, -zv);
        zv = zn;
    }
    #undef WDOT

    // ---- write p (z0..z3) and f (z4..z7) ----
    {
        float* ob = out + b * 100;
        if (l < 4)      ob[l * 5 + t]            = 100.f * zv;
        else if (l < 8) ob[20 + (l - 4) * 5 + t] = 100.f * zv;
    }
}

extern "C" void kernel_launch(void* const* d_in, const int* in_sizes, int n_in,
                              void* d_out, int out_size, void* d_ws, size_t ws_size,
                              hipStream_t stream) {
    const float* xtraj = (const float*)d_in[0];
    const float* x     = (const float*)d_in[1];
    const float* x_img = (const float*)d_in[2];
    const float* cw1 = (const float*)d_in[3];
    const float* cb1 = (const float*)d_in[4];
    const float* cw2 = (const float*)d_in[5];
    const float* cb2 = (const float*)d_in[6];
    const float* w3  = (const float*)d_in[7];
    const float* b3  = (const float*)d_in[8];
    const float* w4  = (const float*)d_in[9];
    const float* b4  = (const float*)d_in[10];
    const float* pw1 = (const float*)d_in[11];
    const float* pb1 = (const float*)d_in[12];
    const float* pw2 = (const float*)d_in[13];
    const float* pb2 = (const float*)d_in[14];
    const float* pw3 = (const float*)d_in[15];
    const float* pb3 = (const float*)d_in[16];
    const float* vw1 = (const float*)d_in[17];
    const float* vb1 = (const float*)d_in[18];
    const float* vw2 = (const float*)d_in[19];
    const float* vb2 = (const float*)d_in[20];
    const float* vw3 = (const float*)d_in[21];
    const float* vb3 = (const float*)d_in[22];

    float* out = (float*)d_out;
    const int Bn = in_sizes[0] / 45;

    net_kernel<<<Bn, 448, 0, stream>>>(
        xtraj, x, x_img, cw1, cb1, cw2, cb2, w3, b3, w4, b4,
        pw1, pb1, pw2, pb2, pw3, pb3, vw1, vb1, vw2, vb2, vw3, vb3,
        out);
}

// Round 12
// 221.577 us; speedup vs baseline: 1.2283x; 1.0015x over previous
//
#include <hip/hip_runtime.h>

// ---------------------------------------------------------------------------
// LP structure tables (verified rounds 3-11).
// ---------------------------------------------------------------------------
__device__ const signed char AZ_IDX[32][8] = {
    {4,5,6,7,8,9,0,0},{10,11,0,0,0,0,0,0},{4,5,6,7,8,9,10,11},
    {0,12,14,0,0,0,0,0},{2,12,14,0,0,0,0,0},{12,14,0,0,0,0,0,0},
    {1,13,15,0,0,0,0,0},{3,13,15,0,0,0,0,0},{13,15,0,0,0,0,0,0},
    {16,18,4,0,0,0,0,0},{16,18,6,0,0,0,0,0},{17,19,5,0,0,0,0,0},
    {17,19,7,0,0,0,0,0},{20,21,8,0,0,0,0,0},{20,21,10,0,0,0,0,0},
    {22,23,9,0,0,0,0,0},{22,23,11,0,0,0,0,0},
    {0},{0},{0},{0},{0},{0},{0},{0},{0},{0},{0},{0},{0},{0},{0}
};
__device__ const signed char AZ_SEL[32][8] = {
    {1,1,1,1,1,1,0,0},{1,1,0,0,0,0,0,0},{3,4,5,6,7,8,9,10},
    {1,11,13,0,0,0,0,0},{1,12,14,0,0,0,0,0},{1,1,0,0,0,0,0,0},
    {1,13,15,0,0,0,0,0},{1,14,16,0,0,0,0,0},{1,1,0,0,0,0,0,0},
    {17,19,2,0,0,0,0,0},{18,20,2,0,0,0,0,0},{19,21,2,0,0,0,0,0},
    {20,22,2,0,0,0,0,0},{23,25,2,0,0,0,0,0},{24,26,2,0,0,0,0,0},
    {27,29,2,0,0,0,0,0},{28,30,2,0,0,0,0,0},
    {0},{0},{0},{0},{0},{0},{0},{0},{0},{0},{0},{0},{0},{0},{0}
};
__device__ const signed char AT_IDX[32][3] = {
    {3,0,0},{6,0,0},{4,0,0},{7,0,0},
    {0,2,9},{0,2,11},{0,2,10},{0,2,12},{0,2,13},{0,2,15},{1,2,14},{1,2,16},
    {3,4,5},{6,7,8},{3,4,5},{6,7,8},
    {9,10,0},{11,12,0},{9,10,0},{11,12,0},
    {13,14,0},{13,14,0},{15,16,0},{15,16,0},
    {0},{0},{0},{0},{0},{0},{0},{0}
};
// Window bases for the 3 float4 mailbox reads (cover all M-row supports).
__device__ const signed char WBA[32] = {0,0,0,0, 4,4,4,4, 4,4,4,4, 0,0,0,0, 4,4,4,4, 8,8,8,8, 0,0,0,0,0,0,0,0};
__device__ const signed char WBB[32] = {12,12,12,12, 8,8,8,8, 8,8,8,8, 12,12,12,12, 16,16,16,16, 20,20,20,20, 0,0,0,0,0,0,0,0};
__device__ const signed char WBC[32] = {0,0,0,0, 16,16,16,16, 20,20,20,20, 0,0,0,0, 0,0,0,0, 0,0,0,0, 0,0,0,0,0,0,0,0};

#define LP_ITERS 400   // R10 FAILED at 300 (absmax 1616): 400 is a correctness constraint.

// ---------------------------------------------------------------------------
// Single fused kernel. 448 threads (7 waves).
// R12: dense/MLP layers k-split 2 ways (2 threads per output neuron,
// partials combined via scratch overlaid on dead s_h1) to halve the
// per-thread serial dot-product chains and double active lanes.
// ---------------------------------------------------------------------------
__global__ __launch_bounds__(448) void net_kernel(
    const float* __restrict__ xtraj, const float* __restrict__ x,
    const float* __restrict__ x_img,
    const float* __restrict__ cw1, const float* __restrict__ cb1,
    const float* __restrict__ cw2, const float* __restrict__ cb2,
    const float* __restrict__ w3, const float* __restrict__ b3,
    const float* __restrict__ w4, const float* __restrict__ b4,
    const float* __restrict__ pw1, const float* __restrict__ pb1,
    const float* __restrict__ pw2, const float* __restrict__ pb2,
    const float* __restrict__ pw3, const float* __restrict__ pb3,
    const float* __restrict__ vw1, const float* __restrict__ vb1,
    const float* __restrict__ vw2, const float* __restrict__ vb2,
    const float* __restrict__ vw3, const float* __restrict__ vb3,
    float* __restrict__ out)
{
    const int b = blockIdx.x;
    const int tid = threadIdx.x;

    __shared__ __align__(16) float s_h1[4000];   // conv1 out; later scratch + LP
    __shared__ __align__(16) float s_w2[5000];   // overlay: img[0:2500]; then cw2
    __shared__ __align__(16) float s_h2[320];
    __shared__ float s_hc[145];
    __shared__ float s_t1[152];
    __shared__ float s_m1[256];
    __shared__ float s_m2[256];

    float* Lb = s_h1;
    float* s_pr = Lb + 2285;
    float* s_vv = Lb + 2305;
    float* S    = Lb + 3000;      // dense partial-sum scratch (dead h1 region)

    float* s_img = s_w2;          // 2500 (dead before conv2-weight reload)

    // ---- phase 0: stage image (float4) ----
    {
        const float4* src = (const float4*)(x_img + (size_t)b * 2500);
        float4* dst = (float4*)s_img;
        for (int i = tid; i < 625; i += 448) dst[i] = src[i];
    }
    __syncthreads();

    // ---- phase 1: conv1 (11x11, 50->40) + maxpool2 + relu, 1 quad/thread ----
    // Weights from global: wave-uniform addresses -> scalar loads.
    if (tid < 400) {
        const int py = tid / 20, px = tid % 20;
        const int C = 2 * px;
        float acc0[10], acc1[10], acc2[10], acc3[10];
        #pragma unroll
        for (int oc = 0; oc < 10; ++oc) { acc0[oc] = 0.f; acc1[oc] = 0.f; acc2[oc] = 0.f; acc3[oc] = 0.f; }
        for (int r = 0; r < 12; ++r) {
            float v[12];
            #pragma unroll
            for (int j = 0; j < 6; ++j) {
                float2 t = *(const float2*)&s_img[(2 * py + r) * 50 + C + 2 * j];
                v[2 * j] = t.x; v[2 * j + 1] = t.y;
            }
            if (r < 11) {
                #pragma unroll
                for (int oc = 0; oc < 10; ++oc) {
                    #pragma unroll
                    for (int kx = 0; kx < 11; ++kx) {
                        float w0 = cw1[oc * 121 + r * 11 + kx];
                        acc0[oc] = fmaf(v[kx], w0, acc0[oc]);
                        acc1[oc] = fmaf(v[kx + 1], w0, acc1[oc]);
                    }
                }
            }
            if (r >= 1) {
                #pragma unroll
                for (int oc = 0; oc < 10; ++oc) {
                    #pragma unroll
                    for (int kx = 0; kx < 11; ++kx) {
                        float w1 = cw1[oc * 121 + (r - 1) * 11 + kx];
                        acc2[oc] = fmaf(v[kx], w1, acc2[oc]);
                        acc3[oc] = fmaf(v[kx + 1], w1, acc3[oc]);
                    }
                }
            }
        }
        #pragma unroll
        for (int oc = 0; oc < 10; ++oc) {
            float m = fmaxf(fmaxf(acc0[oc], acc1[oc]), fmaxf(acc2[oc], acc3[oc]));
            s_h1[oc * 400 + tid] = fmaxf(m + cb1[oc], 0.f);
        }
    }
    __syncthreads();

    // ---- phase 2: reload s_w2 with conv2 weights ----
    {
        const float4* wsrc = (const float4*)cw2;
        float4* wdst = (float4*)s_w2;
        for (int i = tid; i < 1250; i += 448) wdst[i] = wsrc[i];
    }
    __syncthreads();

    // ---- conv2 (5x5, 20->16, 10ic->20oc) + maxpool4 + relu ----
    if (tid < 320) {
        const int oc = tid >> 4, cell = tid & 15;
        const int R0 = (cell >> 2) * 4, C0 = (cell & 3) * 4;
        float acc[16];
        #pragma unroll
        for (int i = 0; i < 16; ++i) acc[i] = 0.f;
        for (int ic = 0; ic < 10; ++ic) {
            const float* hb = &s_h1[ic * 400];
            const float* wb = &s_w2[oc * 250 + ic * 25];
            float v[8][8];
            #pragma unroll
            for (int r = 0; r < 8; ++r) {
                float4 t0 = *(const float4*)&hb[(R0 + r) * 20 + C0];
                float4 t1 = *(const float4*)&hb[(R0 + r) * 20 + C0 + 4];
                v[r][0] = t0.x; v[r][1] = t0.y; v[r][2] = t0.z; v[r][3] = t0.w;
                v[r][4] = t1.x; v[r][5] = t1.y; v[r][6] = t1.z; v[r][7] = t1.w;
            }
            #pragma unroll
            for (int k = 0; k < 5; ++k) {
                #pragma unroll
                for (int kx = 0; kx < 5; ++kx) {
                    float wv = wb[k * 5 + kx];
                    #pragma unroll
                    for (int o = 0; o < 4; ++o) {
                        #pragma unroll
                        for (int cc = 0; cc < 4; ++cc)
                            acc[o * 4 + cc] = fmaf(v[o + k][cc + kx], wv, acc[o * 4 + cc]);
                    }
                }
            }
        }
        float m = acc[0];
        #pragma unroll
        for (int i = 1; i < 16; ++i) m = fmaxf(m, acc[i]);
        s_h2[tid] = fmaxf(m + cb2[oc], 0.f);
    }
    __syncthreads();

    // ---- dense 320 -> 150, relu (2 threads/output, 160 terms each) ----
    if (tid < 300) {
        const int half = tid / 150, o = tid % 150;
        const float* w = w3 + o * 320 + half * 160;
        const float* h = s_h2 + half * 160;
        float a0 = 0.f, a1 = 0.f, a2 = 0.f, a3 = 0.f;
        for (int k = 0; k < 160; k += 4) {
            a0 = fmaf(h[k],     w[k],     a0);
            a1 = fmaf(h[k + 1], w[k + 1], a1);
            a2 = fmaf(h[k + 2], w[k + 2], a2);
            a3 = fmaf(h[k + 3], w[k + 3], a3);
        }
        S[tid] = (a0 + a1) + (a2 + a3);
    }
    __syncthreads();
    if (tid < 150) s_t1[tid] = fmaxf(S[tid] + S[tid + 150] + b3[tid], 0.f);
    __syncthreads();

    // ---- dense 150 -> 100, relu (2 threads/output, 75 terms) + xtraj concat ----
    if (tid < 200) {
        const int half = tid / 100, o = tid % 100;
        const float* w = w4 + o * 150 + half * 75;
        const float* h = s_t1 + half * 75;
        float a0 = 0.f;
        for (int k = 0; k < 75; ++k) a0 = fmaf(h[k], w[k], a0);
        S[tid] = a0;
    } else if (tid >= 200 && tid < 245) {
        s_hc[100 + (tid - 200)] = xtraj[b * 45 + (tid - 200)];
    }
    __syncthreads();
    if (tid < 100) s_hc[tid] = fmaxf(S[tid] + S[tid + 100] + b4[tid], 0.f);
    __syncthreads();

    // ---- MLP layer 1 (145 -> 100, both nets; 2 threads/output) ----
    if (tid < 200) {
        const int half = tid / 100, o = tid % 100;
        const int k0 = half ? 73 : 0, kn = half ? 72 : 73;
        const float* w = pw1 + o * 145 + k0;
        const float* h = s_hc + k0;
        float a0 = 0.f;
        for (int k = 0; k < kn; ++k) a0 = fmaf(h[k], w[k], a0);
        S[tid] = a0;
    } else if (tid < 400) {
        const int i = tid - 200;
        const int half = i / 100, o = i % 100;
        const int k0 = half ? 73 : 0, kn = half ? 72 : 73;
        const float* w = vw1 + o * 145 + k0;
        const float* h = s_hc + k0;
        float a0 = 0.f;
        for (int k = 0; k < kn; ++k) a0 = fmaf(h[k], w[k], a0);
        S[tid] = a0;
    }
    __syncthreads();
    if (tid < 100) s_m1[tid] = fmaxf(S[tid] + S[tid + 100] + pb1[tid], 0.f);
    else if (tid >= 128 && tid < 228) {
        const int i = tid - 128;
        s_m1[tid] = fmaxf(S[200 + i] + S[300 + i] + vb1[i], 0.f);
    }
    __syncthreads();

    // ---- MLP layer 2 (100 -> 100, both nets; 2 threads/output) ----
    if (tid < 200) {
        const int half = tid / 100, o = tid % 100;
        const float* w = pw2 + o * 100 + half * 50;
        const float* h = s_m1 + half * 50;
        float a0 = 0.f;
        for (int k = 0; k < 50; ++k) a0 = fmaf(h[k], w[k], a0);
        S[tid] = a0;
    } else if (tid < 400) {
        const int i = tid - 200;
        const int half = i / 100, o = i % 100;
        const float* w = vw2 + o * 100 + half * 50;
        const float* h = s_m1 + 128 + half * 50;
        float a0 = 0.f;
        for (int k = 0; k < 50; ++k) a0 = fmaf(h[k], w[k], a0);
        S[tid] = a0;
    }
    __syncthreads();
    if (tid < 100) s_m2[tid] = fmaxf(S[tid] + S[tid + 100] + pb2[tid], 0.f);
    else if (tid >= 128 && tid < 228) {
        const int i = tid - 128;
        s_m2[tid] = fmaxf(S[200 + i] + S[300 + i] + vb2[i], 0.f);
    }
    __syncthreads();

    // ---- MLP layer 3 (100 -> 20 / 40; 2 threads/output) ----
    if (tid < 40) {
        const int half = tid / 20, o = tid % 20;
        const float* w = pw3 + o * 100 + half * 50;
        const float* h = s_m2 + half * 50;
        float a0 = 0.f;
        for (int k = 0; k < 50; ++k) a0 = fmaf(h[k], w[k], a0);
        S[tid] = a0;
    } else if (tid >= 128 && tid < 208) {
        const int i = tid - 128;
        const int half = i / 40, o = i % 40;
        const float* w = vw3 + o * 100 + half * 50;
        const float* h = s_m2 + 128 + half * 50;
        float a0 = 0.f;
        for (int k = 0; k < 50; ++k) a0 = fmaf(h[k], w[k], a0);
        S[64 + i] = a0;
    }
    __syncthreads();
    if (tid < 20) {
        float acc = S[tid] + S[tid + 20] + pb3[tid];
        s_pr[tid] = acc;
        out[b * 100 + 40 + tid] = 1000.f * (acc - x[b * 160 + tid]);
    } else if (tid >= 128 && tid < 168) {
        const int i = tid - 128;
        float acc = S[64 + i] + S[64 + i + 40] + vb3[i];
        s_vv[i] = acc;
        out[b * 100 + 60 + i] = 1000.f * (acc - x[b * 160 + 120 + i]);
    }
    __syncthreads();

    // =========================== LP phase ==================================
    if (tid >= 160) return;
    const int t = tid >> 5;
    const int l = tid & 31;
    const float* xt = xtraj + b * 45;
    const float* xb = x + b * 160;

    float* val = Lb + t * 32;
    float* Ag  = Lb + 160 + t * 408;
    float* bg  = Lb + 2200 + t * 17;

    // ---- value table ----
    {
        float v_ = 0.f;
        if (l == 1) v_ = 1.f;
        else if (l == 2) v_ = -1.f;
        else if (l >= 3 && l <= 10) {
            float r0 = xt[t], r1 = xt[5 + t];
            switch (l) {
                case 3:  v_ = r1 - s_pr[10 + t]; break;
                case 4:  v_ = r1 - s_pr[15 + t]; break;
                case 5:  v_ = s_pr[0 + t] - r0;  break;
                case 6:  v_ = s_pr[5 + t] - r0;  break;
                case 7:  v_ = r1 - xb[60 + 10 + t]; break;
                case 8:  v_ = r1 - xb[60 + 15 + t]; break;
                case 9:  v_ = xb[60 + 0 + t] - r0;  break;
                default: v_ = xb[60 + 5 + t] - r0;  break;
            }
        }
        else if (l >= 11 && l <= 16) v_ = -s_vv[5 * (l - 11) + t];
        else if (l >= 17 && l <= 22) v_ = xb[20 + 5 * (l - 17) + t];
        else if (l >= 23 && l <= 30) v_ = xb[80 + 5 * (l - 23) + t];
        val[l] = v_;
    }
    // ---- build dense A, b (intra-wave, DS in-order) ----
    for (int i = l; i < 408; i += 32) Ag[i] = 0.f;
    if (l < 17) {
        #pragma unroll
        for (int k = 0; k < 8; ++k) {
            int sel = AZ_SEL[l][k];
            if (sel != 0) Ag[l * 24 + (int)AZ_IDX[l][k]] = val[sel];
        }
        float bb = 0.f;
        if (l == 0) bb = xt[30 + t];
        else if (l == 1) bb = xt[35 + t];
        else if (l == 2) bb = xt[40 + t];
        else if (l == 5 || l == 8) bb = 1.f;
        bg[l] = bb;
    }

    // ---- numeric 12-slot window coefficients + c = (A^T b)_l ----
    const int bA = WBA[l], bB = WBB[l], bC = WBC[l];
    float cf[12];
    float cc = 0.f;
    #pragma unroll
    for (int k = 0; k < 12; ++k) cf[k] = 0.f;
    if (l < 24) {
        int e0 = AT_IDX[l][0], e1 = AT_IDX[l][1], e2 = AT_IDX[l][2];
        float a0 = Ag[e0 * 24 + l], a1 = Ag[e1 * 24 + l], a2 = Ag[e2 * 24 + l];
        cc = a0 * bg[e0] + a1 * bg[e1] + a2 * bg[e2];
        #pragma unroll
        for (int s = 0; s < 4; ++s)
            cf[s] = a0 * Ag[e0 * 24 + bA + s] + a1 * Ag[e1 * 24 + bA + s] + a2 * Ag[e2 * 24 + bA + s];
        #pragma unroll
        for (int s = 0; s < 4; ++s)
            cf[4 + s] = a0 * Ag[e0 * 24 + bB + s] + a1 * Ag[e1 * 24 + bB + s] + a2 * Ag[e2 * 24 + bB + s];
        if (l >= 4 && l < 12) {
            #pragma unroll
            for (int s = 0; s < 4; ++s)
                cf[8 + s] = a0 * Ag[e0 * 24 + bC + s] + a1 * Ag[e1 * 24 + bC + s] + a2 * Ag[e2 * 24 + bC + s];
        }
    }

    const bool isF  = (l >= 4 && l < 8);
    const bool isNN = (l >= 12);

    float* Zg = Lb + t * 32;   // mailbox (overlays dead val region)

    #define WDOT(vA, vB, vC)                                                    \
        (((cf[0]*vA.x + cf[1]*vA.y) + (cf[2]*vA.z + cf[3]*vA.w)) +              \
         ((cf[4]*vB.x + cf[5]*vB.y) + (cf[6]*vB.z + cf[7]*vB.w)) +              \
         ((cf[8]*vC.x + cf[9]*vC.y) + (cf[10]*vC.z + cf[11]*vC.w)))

    // ---- spectral norm: 25 M-applications, normalize every 5 ----
    float u = (l < 24) ? 1.f : 0.f;
    #pragma unroll 1
    for (int o = 0; o < 5; ++o) {
        #pragma unroll 1
        for (int ii = 0; ii < 5; ++ii) {
            Zg[l] = u;
            float4 vA = *(const float4*)(Zg + bA);
            float4 vB = *(const float4*)(Zg + bB);
            float4 vC = *(const float4*)(Zg + bC);
            u = WDOT(vA, vB, vC);
        }
        float s = u * u;
        s += __shfl_xor(s, 16, 32); s += __shfl_xor(s, 8, 32);
        s += __shfl_xor(s, 4, 32);  s += __shfl_xor(s, 2, 32);
        s += __shfl_xor(s, 1, 32);
        u = u / (sqrtf(s) + 1e-12f);
    }
    float tau;
    {
        Zg[l] = u;
        float4 vA = *(const float4*)(Zg + bA);
        float4 vB = *(const float4*)(Zg + bB);
        float4 vC = *(const float4*)(Zg + bC);
        float w = WDOT(vA, vB, vC);
        float s2 = u * w;   // u^T M u = ||A u||^2
        s2 += __shfl_xor(s2, 16, 32); s2 += __shfl_xor(s2, 8, 32);
        s2 += __shfl_xor(s2, 4, 32);  s2 += __shfl_xor(s2, 2, 32);
        s2 += __shfl_xor(s2, 1, 32);
        tau = 0.9f / (sqrtf(fmaxf(s2, 0.f)) + 1e-8f);
    }

    // ---- prescale by tau^2 ----
    const float t2 = tau * tau;
    #pragma unroll
    for (int k = 0; k < 12; ++k) cf[k] *= t2;
    const float cc2 = cc * t2;

    float zv = 0.f, zbv = 0.f, Q = 0.f;
    #pragma unroll 1
    for (int it = 0; it < LP_ITERS; ++it) {
        Zg[l] = zbv;                                  // ds_write_b32
        float4 vA = *(const float4*)(Zg + bA);        // 3x ds_read_b128
        float4 vB = *(const float4*)(Zg + bB);
        float4 vC = *(const float4*)(Zg + bC);
        float Qm = Q - cc2;                           // overlaps read wait
        float s = WDOT(vA, vB, vC);
        Q = Qm + s;

        float gg = zv - Q;
        float cl = fminf(fmaxf(gg, -tau), tau);       // med3 clamp
        float st = gg - cl;                           // soft-threshold
        float nn = fmaxf(gg, 0.f);
        float zn = isF ? st : (isNN ? nn : gg);
        zbv = fmaf(2.f, zn, -zv);
        zv = zn;
    }
    #undef WDOT

    // ---- write p (z0..z3) and f (z4..z7) ----
    {
        float* ob = out + b * 100;
        if (l < 4)      ob[l * 5 + t]            = 100.f * zv;
        else if (l < 8) ob[20 + (l - 4) * 5 + t] = 100.f * zv;
    }
}

extern "C" void kernel_launch(void* const* d_in, const int* in_sizes, int n_in,
                              void* d_out, int out_size, void* d_ws, size_t ws_size,
                              hipStream_t stream) {
    const float* xtraj = (const float*)d_in[0];
    const float* x     = (const float*)d_in[1];
    const float* x_img = (const float*)d_in[2];
    const float* cw1 = (const float*)d_in[3];
    const float* cb1 = (const float*)d_in[4];
    const float* cw2 = (const float*)d_in[5];
    const float* cb2 = (const float*)d_in[6];
    const float* w3  = (const float*)d_in[7];
    const float* b3  = (const float*)d_in[8];
    const float* w4  = (const float*)d_in[9];
    const float* b4  = (const float*)d_in[10];
    const float* pw1 = (const float*)d_in[11];
    const float* pb1 = (const float*)d_in[12];
    const float* pw2 = (const float*)d_in[13];
    const float* pb2 = (const float*)d_in[14];
    const float* pw3 = (const float*)d_in[15];
    const float* pb3 = (const float*)d_in[16];
    const float* vw1 = (const float*)d_in[17];
    const float* vb1 = (const float*)d_in[18];
    const float* vw2 = (const float*)d_in[19];
    const float* vb2 = (const float*)d_in[20];
    const float* vw3 = (const float*)d_in[21];
    const float* vb3 = (const float*)d_in[22];

    float* out = (float*)d_out;
    const int Bn = in_sizes[0] / 45;

    net_kernel<<<Bn, 448, 0, stream>>>(
        xtraj, x, x_img, cw1, cb1, cw2, cb2, w3, b3, w4, b4,
        pw1, pb1, pw2, pb2, pw3, pb3, vw1, vb1, vw2, vb2, vw3, vb3,
        out);
}